// Round 1
// 404.424 us; speedup vs baseline: 3.5643x; 3.5643x over previous
//
#include <hip/hip_runtime.h>

#define FEAT_IN  500
#define FEAT_OUT 7
#define NXCD     8
#define OVF_CAP  65536

// ============================================================================
// FAST PATH: counting-sort into padded per-dst buckets + gather.
// Atomic budget: 2 per edge (vs 9 per edge in the old atomic-scatter path).
// Memory-side atomic pipe runs at ~1 op/cycle/XCD (~19/ns chip-wide), so
// atomic COUNT is the roofline here, not bandwidth.
// ============================================================================

// K1: one pass over edges. outcnt[src]++ (out-degree for norm_out),
// pos = cursor[dst]++ (in-degree AND bucket slot), bucket[dst*cap+pos] = src.
__global__ void count_scatter_kernel(const int* __restrict__ src, const int* __restrict__ dst,
                                     unsigned* __restrict__ cursor, unsigned* __restrict__ outcnt,
                                     unsigned* __restrict__ bucket, unsigned* __restrict__ ovfcnt,
                                     unsigned* __restrict__ ovf, int E, int cap) {
    int stride = gridDim.x * blockDim.x;
    for (int e = blockIdx.x * blockDim.x + threadIdx.x; e < E; e += stride) {
        int s = src[e], d = dst[e];
        atomicAdd(&outcnt[s], 1u);                       // fire-and-forget
        unsigned pos = atomicAdd(&cursor[d], 1u);        // returning
        if (pos < (unsigned)cap) {
            bucket[(size_t)d * cap + pos] = (unsigned)s;
        } else {
            unsigned o = atomicAdd(ovfcnt, 1u);          // astronomically rare at cap>=64
            if (o < OVF_CAP) { ovf[2 * o] = (unsigned)s; ovf[2 * o + 1] = (unsigned)d; }
        }
    }
}

// K2: feat = (h @ W) * norm_out, padded row stride 8. norm_out fused from outcnt.
__global__ void feat_kernel2(const float* __restrict__ h, const float* __restrict__ W,
                             const unsigned* __restrict__ outcnt,
                             float* __restrict__ feat, int n) {
    __shared__ float Wt[FEAT_OUT * FEAT_IN];  // 14 KB, transposed
    for (int k = threadIdx.x; k < FEAT_IN; k += blockDim.x) {
        #pragma unroll
        for (int j = 0; j < FEAT_OUT; ++j) Wt[j * FEAT_IN + k] = W[k * FEAT_OUT + j];
    }
    __syncthreads();

    const int lane   = threadIdx.x & 63;
    const int wid    = (blockIdx.x * blockDim.x + threadIdx.x) >> 6;
    const int nwaves = (gridDim.x * blockDim.x) >> 6;
    const float4* Wt4 = (const float4*)Wt;  // Wt4[j*125 + v]

    for (int i = wid; i < n; i += nwaves) {
        const float4* hv = (const float4*)(h + (size_t)i * FEAT_IN);  // 125 float4s
        float acc[FEAT_OUT] = {0, 0, 0, 0, 0, 0, 0};
        #pragma unroll
        for (int it = 0; it < 2; ++it) {
            int v = it * 64 + lane;
            if (v < 125) {
                float4 x = hv[v];
                #pragma unroll
                for (int j = 0; j < FEAT_OUT; ++j) {
                    float4 w = Wt4[j * 125 + v];
                    acc[j] += x.x * w.x + x.y * w.y + x.z * w.z + x.w * w.w;
                }
            }
        }
        #pragma unroll
        for (int j = 0; j < FEAT_OUT; ++j) {
            #pragma unroll
            for (int o = 32; o > 0; o >>= 1) acc[j] += __shfl_xor(acc[j], o, 64);
        }
        if (lane == 0) {
            float nrm = rsqrtf(fmaxf((float)outcnt[i], 1.0f));
            float* fo = feat + (size_t)i * 8;
            #pragma unroll
            for (int j = 0; j < FEAT_OUT; ++j) fo[j] = acc[j] * nrm;
        }
    }
}

// K3: gather — 8 lanes per node walk its bucket, gather feat[src] (L2-resident
// 3.2 MB table), shuffle-reduce within the 8-lane group, write out with norm_in
// and bias fused. Zero float atomics, sequential output writes.
__global__ void gather_kernel(const unsigned* __restrict__ cursor, const unsigned* __restrict__ bucket,
                              const float* __restrict__ feat, const float* __restrict__ b,
                              float* __restrict__ out, int n, int cap) {
    int t   = blockIdx.x * blockDim.x + threadIdx.x;
    int gid = t >> 3;
    int l   = t & 7;
    if (gid >= n) return;

    unsigned full = cursor[gid];                 // true in-degree (incl. overflowed edges)
    int cnt = (int)(full < (unsigned)cap ? full : (unsigned)cap);
    const unsigned* bk = bucket + (size_t)gid * cap;

    float acc[FEAT_OUT] = {0, 0, 0, 0, 0, 0, 0};
    for (int e = l; e < cnt; e += 8) {
        unsigned s = bk[e];
        const float4* f = (const float4*)(feat + (size_t)s * 8);
        float4 a = f[0];
        float4 c = f[1];
        acc[0] += a.x; acc[1] += a.y; acc[2] += a.z; acc[3] += a.w;
        acc[4] += c.x; acc[5] += c.y; acc[6] += c.z;
    }
    #pragma unroll
    for (int j = 0; j < FEAT_OUT; ++j) {
        acc[j] += __shfl_xor(acc[j], 1, 64);
        acc[j] += __shfl_xor(acc[j], 2, 64);
        acc[j] += __shfl_xor(acc[j], 4, 64);
    }
    if (l == 0) {
        float nin = rsqrtf(fmaxf((float)full, 1.0f));
        float* o = out + (size_t)gid * FEAT_OUT;
        #pragma unroll
        for (int j = 0; j < FEAT_OUT; ++j) o[j] = acc[j] * nin + b[j];
    }
}

// K4: overflow cleanup (runs only if any bucket exceeded cap; normally empty).
__global__ void ovf_kernel(const unsigned* __restrict__ ovfcnt, const unsigned* __restrict__ ovf,
                           const float* __restrict__ feat, const unsigned* __restrict__ cursor,
                           float* __restrict__ out) {
    unsigned c = ovfcnt[0];
    if (c > OVF_CAP) c = OVF_CAP;
    unsigned stride = gridDim.x * blockDim.x;
    for (unsigned i = blockIdx.x * blockDim.x + threadIdx.x; i < c; i += stride) {
        unsigned s = ovf[2 * i], d = ovf[2 * i + 1];
        float nin = rsqrtf(fmaxf((float)cursor[d], 1.0f));
        const float* f = feat + (size_t)s * 8;
        #pragma unroll
        for (int j = 0; j < FEAT_OUT; ++j)
            atomicAdd(&out[(size_t)d * FEAT_OUT + j], f[j] * nin);
    }
}

// ============================================================================
// FALLBACK PATH (previous verified pipeline) — used only if workspace too small.
// ============================================================================

__device__ __forceinline__ int xcc_id() {
    int x;
    asm volatile("s_getreg_b32 %0, hwreg(HW_REG_XCC_ID)" : "=s"(x));
    return x & (NXCD - 1);
}

__device__ __forceinline__ void atom_add_f(float* p, float v, int priv) {
    if (priv) __hip_atomic_fetch_add(p, v, __ATOMIC_RELAXED, __HIP_MEMORY_SCOPE_WORKGROUP);
    else      atomicAdd(p, v);
}

__device__ __forceinline__ void atom_add_u(unsigned* p, unsigned v, int priv) {
    if (priv) __hip_atomic_fetch_add(p, v, __ATOMIC_RELAXED, __HIP_MEMORY_SCOPE_WORKGROUP);
    else      atomicAdd(p, v);
}

__global__ void degree_kernel(const int* __restrict__ src, const int* __restrict__ dst,
                              unsigned* __restrict__ deg_priv, int E, int n, int priv) {
    unsigned* deg = deg_priv + (priv ? (size_t)xcc_id() * n : 0);
    int stride = gridDim.x * blockDim.x;
    for (int e = blockIdx.x * blockDim.x + threadIdx.x; e < E; e += stride) {
        atom_add_u(&deg[src[e]], 1u, priv);
        atom_add_u(&deg[dst[e]], 1u << 16, priv);
    }
}

__global__ void norm_kernel(const unsigned* __restrict__ deg_priv,
                            float* __restrict__ norm_out, float* __restrict__ norm_in,
                            int n, int ncopies) {
    int i = blockIdx.x * blockDim.x + threadIdx.x;
    if (i < n) {
        unsigned s = 0;
        for (int x = 0; x < ncopies; ++x) s += deg_priv[(size_t)x * n + i];
        norm_out[i] = rsqrtf(fmaxf((float)(s & 0xffffu), 1.0f));
        norm_in[i]  = rsqrtf(fmaxf((float)(s >> 16), 1.0f));
    }
}

__global__ void feat_kernel(const float* __restrict__ h, const float* __restrict__ W,
                            const float* __restrict__ norm_out,
                            float* __restrict__ feat, int n) {
    __shared__ float Wt[FEAT_OUT * FEAT_IN];
    for (int k = threadIdx.x; k < FEAT_IN; k += blockDim.x) {
        #pragma unroll
        for (int j = 0; j < FEAT_OUT; ++j) Wt[j * FEAT_IN + k] = W[k * FEAT_OUT + j];
    }
    __syncthreads();

    const int lane   = threadIdx.x & 63;
    const int wid    = (blockIdx.x * blockDim.x + threadIdx.x) >> 6;
    const int nwaves = (gridDim.x * blockDim.x) >> 6;
    const float4* Wt4 = (const float4*)Wt;

    for (int i = wid; i < n; i += nwaves) {
        const float4* hv = (const float4*)(h + (size_t)i * FEAT_IN);
        float acc[FEAT_OUT] = {0, 0, 0, 0, 0, 0, 0};
        #pragma unroll
        for (int it = 0; it < 2; ++it) {
            int v = it * 64 + lane;
            if (v < 125) {
                float4 x = hv[v];
                #pragma unroll
                for (int j = 0; j < FEAT_OUT; ++j) {
                    float4 w = Wt4[j * 125 + v];
                    acc[j] += x.x * w.x + x.y * w.y + x.z * w.z + x.w * w.w;
                }
            }
        }
        #pragma unroll
        for (int j = 0; j < FEAT_OUT; ++j) {
            #pragma unroll
            for (int o = 32; o > 0; o >>= 1) acc[j] += __shfl_xor(acc[j], o, 64);
        }
        if (lane == 0) {
            float nrm = norm_out[i];
            float* fo = feat + (size_t)i * 8;
            #pragma unroll
            for (int j = 0; j < FEAT_OUT; ++j) fo[j] = acc[j] * nrm;
        }
    }
}

__global__ void scatter_kernel(const int* __restrict__ src, const int* __restrict__ dst,
                               const float* __restrict__ feat, float* __restrict__ out_priv,
                               int E, int n, int priv) {
    float* out = out_priv + (priv ? (size_t)xcc_id() * ((size_t)n * FEAT_OUT) : 0);
    int stride = gridDim.x * blockDim.x;
    for (int e = blockIdx.x * blockDim.x + threadIdx.x; e < E; e += stride) {
        int s = src[e], d = dst[e];
        const float* f = feat + (size_t)s * 8;
        float4 a = *(const float4*)(f);
        float4 c = *(const float4*)(f + 4);
        float* o = out + (size_t)d * FEAT_OUT;
        atom_add_f(o + 0, a.x, priv);
        atom_add_f(o + 1, a.y, priv);
        atom_add_f(o + 2, a.z, priv);
        atom_add_f(o + 3, a.w, priv);
        atom_add_f(o + 4, c.x, priv);
        atom_add_f(o + 5, c.y, priv);
        atom_add_f(o + 6, c.z, priv);
    }
}

__global__ void final_kernel(const float* __restrict__ out_priv, const float* __restrict__ norm_in,
                             const float* __restrict__ b, float* __restrict__ out,
                             int n, int ncopies) {
    int i = blockIdx.x * blockDim.x + threadIdx.x;
    if (i < n) {
        float acc[FEAT_OUT] = {0, 0, 0, 0, 0, 0, 0};
        for (int x = 0; x < ncopies; ++x) {
            const float* p = out_priv + (size_t)x * n * FEAT_OUT + (size_t)i * FEAT_OUT;
            #pragma unroll
            for (int j = 0; j < FEAT_OUT; ++j) acc[j] += p[j];
        }
        float nin = norm_in[i];
        float* o = out + (size_t)i * FEAT_OUT;
        #pragma unroll
        for (int j = 0; j < FEAT_OUT; ++j) o[j] = acc[j] * nin + b[j];
    }
}

// ============================================================================

extern "C" void kernel_launch(void* const* d_in, const int* in_sizes, int n_in,
                              void* d_out, int out_size, void* d_ws, size_t ws_size,
                              hipStream_t stream) {
    const float* h   = (const float*)d_in[0];
    const float* W   = (const float*)d_in[1];
    const float* b   = (const float*)d_in[2];
    const int*   src = (const int*)d_in[3];
    const int*   dst = (const int*)d_in[4];

    const int n = in_sizes[0] / FEAT_IN;   // 100000
    const int E = in_sizes[3];             // 3300000
    float* out = (float*)d_out;

    // ---- fast path workspace layout ----
    // [cursor n u32][outcnt n u32][ovfcnt 16 u32][feat n*8 f32][ovf 2*OVF u32][bucket n*cap u32]
    size_t fixed = (size_t)n * 4 * 2 + 64 + (size_t)n * 8 * 4 + (size_t)OVF_CAP * 8;
    int cap = 0;
    if (ws_size > fixed) cap = (int)((ws_size - fixed) / ((size_t)n * 4));
    if (cap > 96) cap = 96;

    if (cap >= 64) {
        unsigned* cursor = (unsigned*)d_ws;
        unsigned* outcnt = cursor + n;
        unsigned* ovfcnt = outcnt + n;                       // 16-u32 slot
        float*    feat   = (float*)(ovfcnt + 16);
        unsigned* ovf    = (unsigned*)(feat + (size_t)n * 8);
        unsigned* bucket = ovf + (size_t)OVF_CAP * 2;

        // zero cursor + outcnt + ovfcnt only (bucket/ovf guarded by counts)
        hipMemsetAsync(d_ws, 0, (size_t)n * 8 + 64, stream);

        count_scatter_kernel<<<4096, 256, 0, stream>>>(src, dst, cursor, outcnt, bucket,
                                                       ovfcnt, ovf, E, cap);
        feat_kernel2<<<2048, 256, 0, stream>>>(h, W, outcnt, feat, n);
        gather_kernel<<<((size_t)n * 8 + 255) / 256, 256, 0, stream>>>(cursor, bucket, feat,
                                                                       b, out, n, cap);
        ovf_kernel<<<16, 256, 0, stream>>>(ovfcnt, ovf, feat, cursor, out);
        return;
    }

    // ---- fallback: previous verified pipeline ----
    size_t need8 = (size_t)NXCD * n * 4 + (size_t)NXCD * n * FEAT_OUT * 4
                 + (size_t)n * 4 * 2 + (size_t)n * 8 * 4;
    int priv = (ws_size >= need8) ? 1 : 0;
    int NC = priv ? NXCD : 1;

    unsigned* deg_priv = (unsigned*)d_ws;
    float*    out_priv = (float*)(deg_priv + (size_t)NC * n);
    float*    norm_out = out_priv + (size_t)NC * n * FEAT_OUT;
    float*    norm_in  = norm_out + n;
    float*    feat     = norm_in + n;

    hipMemsetAsync(d_ws, 0, (size_t)NC * n * 4 * (1 + FEAT_OUT), stream);

    degree_kernel<<<4096, 256, 0, stream>>>(src, dst, deg_priv, E, n, priv);
    norm_kernel<<<(n + 255) / 256, 256, 0, stream>>>(deg_priv, norm_out, norm_in, n, NC);
    feat_kernel<<<2048, 256, 0, stream>>>(h, W, norm_out, feat, n);
    scatter_kernel<<<4096, 256, 0, stream>>>(src, dst, feat, out_priv, E, n, priv);
    final_kernel<<<(n + 255) / 256, 256, 0, stream>>>(out_priv, norm_in, b, out, NC == 1 ? n : n, NC);
}

// Round 2
// 340.246 us; speedup vs baseline: 4.2366x; 1.1886x over previous
//
#include <hip/hip_runtime.h>

#define FEAT_IN  500
#define FEAT_OUT 7
#define NXCD     8
#define OVF_CAP  65536

// ---- new partition path params ----
#define RNG     512          // nodes per coarse bucket
#define LG      9            // log2(RNG)
#define NB_MAX  256          // max coarse buckets (n <= 131072)
#define OVF_D   16384
#define OVF_S   65536
#define NBLK1   512          // partition blocks

// ============================================================================
// PRIMARY PATH: block-aggregated two-level partition. Global atomics: ~100K
// total (vs 6.6M for per-edge counting) — the memory-side atomic pipe runs at
// ~20 ops/ns chip-wide and was 80% of round-1's runtime.
// ============================================================================

__global__ void init_kernel(unsigned long long* __restrict__ gcur,
                            unsigned* __restrict__ ovfc, int nb, int cap) {
    int i = blockIdx.x * blockDim.x + threadIdx.x;
    if (i < nb) {
        unsigned long long v = (unsigned long long)(unsigned)(i * cap);
        gcur[i] = (v << 32) | v;   // high: src cursor, low: dst cursor
    }
    if (i < 16) ovfc[i] = 0;
}

// P1: partition edges into coarse dst-buckets (packed u32) and src-buckets (u16
// local id). Per-block LDS histogram, one u64 global atomic per (block,bucket).
__global__ void partition_kernel(const int* __restrict__ src, const int* __restrict__ dst,
                                 unsigned long long* __restrict__ gcur,
                                 unsigned* __restrict__ dstpart, unsigned short* __restrict__ srcpart,
                                 unsigned* __restrict__ ovfc, unsigned* __restrict__ ovf_d,
                                 unsigned* __restrict__ ovf_s, int E, int nb, int cap) {
    __shared__ unsigned cd[NB_MAX], cs[NB_MAX], sd[NB_MAX], ss[NB_MAX];
    int chunk = (E + gridDim.x - 1) / gridDim.x;
    int e0 = blockIdx.x * chunk;
    int e1 = min(e0 + chunk, E);

    for (int i = threadIdx.x; i < nb; i += blockDim.x) { cd[i] = 0; cs[i] = 0; }
    __syncthreads();

    for (int e = e0 + threadIdx.x; e < e1; e += blockDim.x) {
        atomicAdd(&cd[dst[e] >> LG], 1u);
        atomicAdd(&cs[src[e] >> LG], 1u);
    }
    __syncthreads();

    for (int i = threadIdx.x; i < nb; i += blockDim.x) {
        unsigned long long pk = ((unsigned long long)cs[i] << 32) | (unsigned long long)cd[i];
        unsigned long long old = atomicAdd(&gcur[i], pk);   // one atomic reserves BOTH ranges
        sd[i] = (unsigned)old;
        ss[i] = (unsigned)(old >> 32);
        cd[i] = 0; cs[i] = 0;       // reuse as block-local cursors
    }
    __syncthreads();

    for (int e = e0 + threadIdx.x; e < e1; e += blockDim.x) {
        int s = src[e], d = dst[e];
        int bd = d >> LG, bs = s >> LG;
        unsigned pd = sd[bd] + atomicAdd(&cd[bd], 1u);
        if (pd < (unsigned)((bd + 1) * cap)) {
            dstpart[pd] = ((unsigned)(d & (RNG - 1)) << 17) | (unsigned)s;
        } else {
            unsigned o = atomicAdd(&ovfc[0], 1u);
            if (o < OVF_D) { ovf_d[2 * o] = (unsigned)s; ovf_d[2 * o + 1] = (unsigned)d; }
        }
        unsigned ps = ss[bs] + atomicAdd(&cs[bs], 1u);
        if (ps < (unsigned)((bs + 1) * cap)) {
            srcpart[ps] = (unsigned short)(s & (RNG - 1));
        } else {
            unsigned o = atomicAdd(&ovfc[1], 1u);
            if (o < OVF_S) ovf_s[o] = (unsigned)s;
        }
    }
}

// P2b: exact out-degree histogram per coarse bucket (node-filtered sub-blocks).
__global__ void srccount_kernel(const unsigned long long* __restrict__ gcur,
                                const unsigned short* __restrict__ srcpart,
                                unsigned* __restrict__ outcnt, int cap) {
    int b = blockIdx.x >> 1, sp = blockIdx.x & 1;
    __shared__ unsigned hist[256];
    hist[threadIdx.x] = 0;
    __syncthreads();
    unsigned base = (unsigned)(b * cap);
    unsigned tot = (unsigned)(gcur[b] >> 32) - base;
    unsigned scnt = tot < (unsigned)cap ? tot : (unsigned)cap;
    for (unsigned i = threadIdx.x; i < scnt; i += blockDim.x) {
        unsigned sl = srcpart[base + i];
        if ((int)(sl >> 8) == sp) atomicAdd(&hist[sl & 255u], 1u);
    }
    __syncthreads();
    outcnt[b * RNG + sp * 256 + threadIdx.x] = hist[threadIdx.x];
}

__global__ void ovf_s_kernel(const unsigned* __restrict__ ovfc, const unsigned* __restrict__ ovf_s,
                             unsigned* __restrict__ outcnt) {
    unsigned c = ovfc[1]; if (c > OVF_S) c = OVF_S;
    unsigned stride = gridDim.x * blockDim.x;
    for (unsigned i = blockIdx.x * blockDim.x + threadIdx.x; i < c; i += stride)
        atomicAdd(&outcnt[ovf_s[i]], 1u);
}

// P2a: per coarse bucket (×2 node-filtered sub-blocks), gather feat[src] and
// accumulate into LDS (stride-9 pad vs bank conflicts); in-degree in slot 7.
__global__ void accum_kernel(const unsigned long long* __restrict__ gcur,
                             const unsigned* __restrict__ dstpart,
                             const float* __restrict__ feat,
                             float* __restrict__ accf, int cap) {
    int b = blockIdx.x >> 1, sp = blockIdx.x & 1;
    __shared__ float acc[256 * 9];
    for (int i = threadIdx.x; i < 256 * 9; i += blockDim.x) acc[i] = 0.f;
    __syncthreads();
    unsigned base = (unsigned)(b * cap);
    unsigned tot = (unsigned)(gcur[b] & 0xffffffffu) - base;
    unsigned ecnt = tot < (unsigned)cap ? tot : (unsigned)cap;
    for (unsigned i = threadIdx.x; i < ecnt; i += blockDim.x) {
        unsigned pk = dstpart[base + i];
        unsigned dl = pk >> 17;
        if ((int)(dl >> 8) == sp) {
            const float4* f = (const float4*)(feat + (size_t)(pk & 0x1FFFFu) * 8);
            float4 a = f[0], c = f[1];
            float* p = acc + (dl & 255u) * 9;
            atomicAdd(p + 0, a.x); atomicAdd(p + 1, a.y); atomicAdd(p + 2, a.z); atomicAdd(p + 3, a.w);
            atomicAdd(p + 4, c.x); atomicAdd(p + 5, c.y); atomicAdd(p + 6, c.z); atomicAdd(p + 7, 1.0f);
        }
    }
    __syncthreads();
    float* dstp = accf + ((size_t)b * RNG + (size_t)sp * 256) * 8;
    for (int i = threadIdx.x; i < 2048; i += blockDim.x) {
        int l = i >> 3, j = i & 7;
        dstp[i] = acc[l * 9 + j];
    }
}

__global__ void ovf_d_kernel(const unsigned* __restrict__ ovfc, const unsigned* __restrict__ ovf_d,
                             const float* __restrict__ feat, float* __restrict__ accf) {
    unsigned c = ovfc[0]; if (c > OVF_D) c = OVF_D;
    unsigned stride = gridDim.x * blockDim.x;
    for (unsigned i = blockIdx.x * blockDim.x + threadIdx.x; i < c; i += stride) {
        unsigned s = ovf_d[2 * i], d = ovf_d[2 * i + 1];
        const float* f = feat + (size_t)s * 8;
        float* p = accf + (size_t)d * 8;
        #pragma unroll
        for (int j = 0; j < FEAT_OUT; ++j) atomicAdd(p + j, f[j]);
        atomicAdd(p + 7, 1.0f);
    }
}

__global__ void final2_kernel(const float* __restrict__ accf, const float* __restrict__ b,
                              float* __restrict__ out, int n) {
    int i = blockIdx.x * blockDim.x + threadIdx.x;
    if (i < n) {
        const float* p = accf + (size_t)i * 8;
        float nin = rsqrtf(fmaxf(p[7], 1.0f));
        float* o = out + (size_t)i * FEAT_OUT;
        #pragma unroll
        for (int j = 0; j < FEAT_OUT; ++j) o[j] = p[j] * nin + b[j];
    }
}

// K2: feat = (h @ W) * norm_out, padded row stride 8. norm_out fused from outcnt.
__global__ void feat_kernel2(const float* __restrict__ h, const float* __restrict__ W,
                             const unsigned* __restrict__ outcnt,
                             float* __restrict__ feat, int n) {
    __shared__ float Wt[FEAT_OUT * FEAT_IN];  // 14 KB, transposed
    for (int k = threadIdx.x; k < FEAT_IN; k += blockDim.x) {
        #pragma unroll
        for (int j = 0; j < FEAT_OUT; ++j) Wt[j * FEAT_IN + k] = W[k * FEAT_OUT + j];
    }
    __syncthreads();

    const int lane   = threadIdx.x & 63;
    const int wid    = (blockIdx.x * blockDim.x + threadIdx.x) >> 6;
    const int nwaves = (gridDim.x * blockDim.x) >> 6;
    const float4* Wt4 = (const float4*)Wt;  // Wt4[j*125 + v]

    for (int i = wid; i < n; i += nwaves) {
        const float4* hv = (const float4*)(h + (size_t)i * FEAT_IN);  // 125 float4s
        float acc[FEAT_OUT] = {0, 0, 0, 0, 0, 0, 0};
        #pragma unroll
        for (int it = 0; it < 2; ++it) {
            int v = it * 64 + lane;
            if (v < 125) {
                float4 x = hv[v];
                #pragma unroll
                for (int j = 0; j < FEAT_OUT; ++j) {
                    float4 w = Wt4[j * 125 + v];
                    acc[j] += x.x * w.x + x.y * w.y + x.z * w.z + x.w * w.w;
                }
            }
        }
        #pragma unroll
        for (int j = 0; j < FEAT_OUT; ++j) {
            #pragma unroll
            for (int o = 32; o > 0; o >>= 1) acc[j] += __shfl_xor(acc[j], o, 64);
        }
        if (lane == 0) {
            float nrm = rsqrtf(fmaxf((float)outcnt[i], 1.0f));
            float* fo = feat + (size_t)i * 8;
            #pragma unroll
            for (int j = 0; j < FEAT_OUT; ++j) fo[j] = acc[j] * nrm;
        }
    }
}

// ============================================================================
// SECONDARY PATH (round-1 verified): per-edge counting-sort buckets + gather.
// ============================================================================

__global__ void count_scatter_kernel(const int* __restrict__ src, const int* __restrict__ dst,
                                     unsigned* __restrict__ cursor, unsigned* __restrict__ outcnt,
                                     unsigned* __restrict__ bucket, unsigned* __restrict__ ovfcnt,
                                     unsigned* __restrict__ ovf, int E, int cap) {
    int stride = gridDim.x * blockDim.x;
    for (int e = blockIdx.x * blockDim.x + threadIdx.x; e < E; e += stride) {
        int s = src[e], d = dst[e];
        atomicAdd(&outcnt[s], 1u);
        unsigned pos = atomicAdd(&cursor[d], 1u);
        if (pos < (unsigned)cap) {
            bucket[(size_t)d * cap + pos] = (unsigned)s;
        } else {
            unsigned o = atomicAdd(ovfcnt, 1u);
            if (o < OVF_CAP) { ovf[2 * o] = (unsigned)s; ovf[2 * o + 1] = (unsigned)d; }
        }
    }
}

__global__ void gather_kernel(const unsigned* __restrict__ cursor, const unsigned* __restrict__ bucket,
                              const float* __restrict__ feat, const float* __restrict__ b,
                              float* __restrict__ out, int n, int cap) {
    int t   = blockIdx.x * blockDim.x + threadIdx.x;
    int gid = t >> 3;
    int l   = t & 7;
    if (gid >= n) return;

    unsigned full = cursor[gid];
    int cnt = (int)(full < (unsigned)cap ? full : (unsigned)cap);
    const unsigned* bk = bucket + (size_t)gid * cap;

    float acc[FEAT_OUT] = {0, 0, 0, 0, 0, 0, 0};
    for (int e = l; e < cnt; e += 8) {
        unsigned s = bk[e];
        const float4* f = (const float4*)(feat + (size_t)s * 8);
        float4 a = f[0];
        float4 c = f[1];
        acc[0] += a.x; acc[1] += a.y; acc[2] += a.z; acc[3] += a.w;
        acc[4] += c.x; acc[5] += c.y; acc[6] += c.z;
    }
    #pragma unroll
    for (int j = 0; j < FEAT_OUT; ++j) {
        acc[j] += __shfl_xor(acc[j], 1, 64);
        acc[j] += __shfl_xor(acc[j], 2, 64);
        acc[j] += __shfl_xor(acc[j], 4, 64);
    }
    if (l == 0) {
        float nin = rsqrtf(fmaxf((float)full, 1.0f));
        float* o = out + (size_t)gid * FEAT_OUT;
        #pragma unroll
        for (int j = 0; j < FEAT_OUT; ++j) o[j] = acc[j] * nin + b[j];
    }
}

__global__ void ovf_kernel(const unsigned* __restrict__ ovfcnt, const unsigned* __restrict__ ovf,
                           const float* __restrict__ feat, const unsigned* __restrict__ cursor,
                           float* __restrict__ out) {
    unsigned c = ovfcnt[0];
    if (c > OVF_CAP) c = OVF_CAP;
    unsigned stride = gridDim.x * blockDim.x;
    for (unsigned i = blockIdx.x * blockDim.x + threadIdx.x; i < c; i += stride) {
        unsigned s = ovf[2 * i], d = ovf[2 * i + 1];
        float nin = rsqrtf(fmaxf((float)cursor[d], 1.0f));
        const float* f = feat + (size_t)s * 8;
        #pragma unroll
        for (int j = 0; j < FEAT_OUT; ++j)
            atomicAdd(&out[(size_t)d * FEAT_OUT + j], f[j] * nin);
    }
}

// ============================================================================
// TERTIARY PATH (round-0 verified): privatized atomic scatter.
// ============================================================================

__device__ __forceinline__ int xcc_id() {
    int x;
    asm volatile("s_getreg_b32 %0, hwreg(HW_REG_XCC_ID)" : "=s"(x));
    return x & (NXCD - 1);
}

__device__ __forceinline__ void atom_add_f(float* p, float v, int priv) {
    if (priv) __hip_atomic_fetch_add(p, v, __ATOMIC_RELAXED, __HIP_MEMORY_SCOPE_WORKGROUP);
    else      atomicAdd(p, v);
}

__device__ __forceinline__ void atom_add_u(unsigned* p, unsigned v, int priv) {
    if (priv) __hip_atomic_fetch_add(p, v, __ATOMIC_RELAXED, __HIP_MEMORY_SCOPE_WORKGROUP);
    else      atomicAdd(p, v);
}

__global__ void degree_kernel(const int* __restrict__ src, const int* __restrict__ dst,
                              unsigned* __restrict__ deg_priv, int E, int n, int priv) {
    unsigned* deg = deg_priv + (priv ? (size_t)xcc_id() * n : 0);
    int stride = gridDim.x * blockDim.x;
    for (int e = blockIdx.x * blockDim.x + threadIdx.x; e < E; e += stride) {
        atom_add_u(&deg[src[e]], 1u, priv);
        atom_add_u(&deg[dst[e]], 1u << 16, priv);
    }
}

__global__ void norm_kernel(const unsigned* __restrict__ deg_priv,
                            float* __restrict__ norm_out, float* __restrict__ norm_in,
                            int n, int ncopies) {
    int i = blockIdx.x * blockDim.x + threadIdx.x;
    if (i < n) {
        unsigned s = 0;
        for (int x = 0; x < ncopies; ++x) s += deg_priv[(size_t)x * n + i];
        norm_out[i] = rsqrtf(fmaxf((float)(s & 0xffffu), 1.0f));
        norm_in[i]  = rsqrtf(fmaxf((float)(s >> 16), 1.0f));
    }
}

__global__ void feat_kernel(const float* __restrict__ h, const float* __restrict__ W,
                            const float* __restrict__ norm_out,
                            float* __restrict__ feat, int n) {
    __shared__ float Wt[FEAT_OUT * FEAT_IN];
    for (int k = threadIdx.x; k < FEAT_IN; k += blockDim.x) {
        #pragma unroll
        for (int j = 0; j < FEAT_OUT; ++j) Wt[j * FEAT_IN + k] = W[k * FEAT_OUT + j];
    }
    __syncthreads();

    const int lane   = threadIdx.x & 63;
    const int wid    = (blockIdx.x * blockDim.x + threadIdx.x) >> 6;
    const int nwaves = (gridDim.x * blockDim.x) >> 6;
    const float4* Wt4 = (const float4*)Wt;

    for (int i = wid; i < n; i += nwaves) {
        const float4* hv = (const float4*)(h + (size_t)i * FEAT_IN);
        float acc[FEAT_OUT] = {0, 0, 0, 0, 0, 0, 0};
        #pragma unroll
        for (int it = 0; it < 2; ++it) {
            int v = it * 64 + lane;
            if (v < 125) {
                float4 x = hv[v];
                #pragma unroll
                for (int j = 0; j < FEAT_OUT; ++j) {
                    float4 w = Wt4[j * 125 + v];
                    acc[j] += x.x * w.x + x.y * w.y + x.z * w.z + x.w * w.w;
                }
            }
        }
        #pragma unroll
        for (int j = 0; j < FEAT_OUT; ++j) {
            #pragma unroll
            for (int o = 32; o > 0; o >>= 1) acc[j] += __shfl_xor(acc[j], o, 64);
        }
        if (lane == 0) {
            float nrm = norm_out[i];
            float* fo = feat + (size_t)i * 8;
            #pragma unroll
            for (int j = 0; j < FEAT_OUT; ++j) fo[j] = acc[j] * nrm;
        }
    }
}

__global__ void scatter_kernel(const int* __restrict__ src, const int* __restrict__ dst,
                               const float* __restrict__ feat, float* __restrict__ out_priv,
                               int E, int n, int priv) {
    float* out = out_priv + (priv ? (size_t)xcc_id() * ((size_t)n * FEAT_OUT) : 0);
    int stride = gridDim.x * blockDim.x;
    for (int e = blockIdx.x * blockDim.x + threadIdx.x; e < E; e += stride) {
        int s = src[e], d = dst[e];
        const float* f = feat + (size_t)s * 8;
        float4 a = *(const float4*)(f);
        float4 c = *(const float4*)(f + 4);
        float* o = out + (size_t)d * FEAT_OUT;
        atom_add_f(o + 0, a.x, priv);
        atom_add_f(o + 1, a.y, priv);
        atom_add_f(o + 2, a.z, priv);
        atom_add_f(o + 3, a.w, priv);
        atom_add_f(o + 4, c.x, priv);
        atom_add_f(o + 5, c.y, priv);
        atom_add_f(o + 6, c.z, priv);
    }
}

__global__ void final_kernel(const float* __restrict__ out_priv, const float* __restrict__ norm_in,
                             const float* __restrict__ b, float* __restrict__ out,
                             int n, int ncopies) {
    int i = blockIdx.x * blockDim.x + threadIdx.x;
    if (i < n) {
        float acc[FEAT_OUT] = {0, 0, 0, 0, 0, 0, 0};
        for (int x = 0; x < ncopies; ++x) {
            const float* p = out_priv + (size_t)x * n * FEAT_OUT + (size_t)i * FEAT_OUT;
            #pragma unroll
            for (int j = 0; j < FEAT_OUT; ++j) acc[j] += p[j];
        }
        float nin = norm_in[i];
        float* o = out + (size_t)i * FEAT_OUT;
        #pragma unroll
        for (int j = 0; j < FEAT_OUT; ++j) o[j] = acc[j] * nin + b[j];
    }
}

// ============================================================================

extern "C" void kernel_launch(void* const* d_in, const int* in_sizes, int n_in,
                              void* d_out, int out_size, void* d_ws, size_t ws_size,
                              hipStream_t stream) {
    const float* h   = (const float*)d_in[0];
    const float* W   = (const float*)d_in[1];
    const float* b   = (const float*)d_in[2];
    const int*   src = (const int*)d_in[3];
    const int*   dst = (const int*)d_in[4];

    const int n = in_sizes[0] / FEAT_IN;   // 100000
    const int E = in_sizes[3];             // 3300000
    float* out = (float*)d_out;

    // ---------------- primary: partition path ----------------
    int nb = (n + RNG - 1) / RNG;          // 196
    if (nb <= NB_MAX) {
        size_t npad = (size_t)nb * RNG;
        // layout: gcur(2048) | ovfc(64) | outcnt npad u32 | ovf_s | ovf_d |
        //         accf npad*8 f32 | feat n*8 f32 | dstpart nb*cap u32 | srcpart nb*cap u16
        size_t fixed = 2048 + 64 + npad * 4 + (size_t)OVF_S * 4 + (size_t)OVF_D * 8
                     + npad * 32 + (size_t)n * 32;
        long cap = 0;
        if (ws_size > fixed) cap = (long)((ws_size - fixed) / ((size_t)nb * 6));
        cap &= ~63L;
        if (cap > 24576) cap = 24576;
        long capmin = (long)(E / nb) + (long)(E / nb) / 16 + 640;  // mean + ~14 sigma

        if (cap >= capmin) {
            char* p = (char*)d_ws;
            unsigned long long* gcur = (unsigned long long*)p;  p += 2048;
            unsigned* ovfc    = (unsigned*)p;                   p += 64;
            unsigned* outcnt  = (unsigned*)p;                   p += npad * 4;
            unsigned* ovf_s   = (unsigned*)p;                   p += (size_t)OVF_S * 4;
            unsigned* ovf_d   = (unsigned*)p;                   p += (size_t)OVF_D * 8;
            float*    accf    = (float*)p;                      p += npad * 32;
            float*    feat    = (float*)p;                      p += (size_t)n * 32;
            unsigned* dstpart = (unsigned*)p;                   p += (size_t)nb * cap * 4;
            unsigned short* srcpart = (unsigned short*)p;

            init_kernel<<<1, 256, 0, stream>>>(gcur, ovfc, nb, (int)cap);
            partition_kernel<<<NBLK1, 256, 0, stream>>>(src, dst, gcur, dstpart, srcpart,
                                                        ovfc, ovf_d, ovf_s, E, nb, (int)cap);
            srccount_kernel<<<nb * 2, 256, 0, stream>>>(gcur, srcpart, outcnt, (int)cap);
            ovf_s_kernel<<<4, 256, 0, stream>>>(ovfc, ovf_s, outcnt);
            feat_kernel2<<<2048, 256, 0, stream>>>(h, W, outcnt, feat, n);
            accum_kernel<<<nb * 2, 512, 0, stream>>>(gcur, dstpart, feat, accf, (int)cap);
            ovf_d_kernel<<<4, 256, 0, stream>>>(ovfc, ovf_d, feat, accf);
            final2_kernel<<<(n + 255) / 256, 256, 0, stream>>>(accf, b, out, n);
            return;
        }
    }

    // ---------------- secondary: round-1 bucket path ----------------
    size_t fixed = (size_t)n * 4 * 2 + 64 + (size_t)n * 8 * 4 + (size_t)OVF_CAP * 8;
    int cap = 0;
    if (ws_size > fixed) cap = (int)((ws_size - fixed) / ((size_t)n * 4));
    if (cap > 96) cap = 96;

    if (cap >= 64) {
        unsigned* cursor = (unsigned*)d_ws;
        unsigned* outcnt = cursor + n;
        unsigned* ovfcnt = outcnt + n;
        float*    feat   = (float*)(ovfcnt + 16);
        unsigned* ovf    = (unsigned*)(feat + (size_t)n * 8);
        unsigned* bucket = ovf + (size_t)OVF_CAP * 2;

        hipMemsetAsync(d_ws, 0, (size_t)n * 8 + 64, stream);

        count_scatter_kernel<<<4096, 256, 0, stream>>>(src, dst, cursor, outcnt, bucket,
                                                       ovfcnt, ovf, E, cap);
        feat_kernel2<<<2048, 256, 0, stream>>>(h, W, outcnt, feat, n);
        gather_kernel<<<((size_t)n * 8 + 255) / 256, 256, 0, stream>>>(cursor, bucket, feat,
                                                                       b, out, n, cap);
        ovf_kernel<<<16, 256, 0, stream>>>(ovfcnt, ovf, feat, cursor, out);
        return;
    }

    // ---------------- tertiary: round-0 atomic path ----------------
    size_t need8 = (size_t)NXCD * n * 4 + (size_t)NXCD * n * FEAT_OUT * 4
                 + (size_t)n * 4 * 2 + (size_t)n * 8 * 4;
    int priv = (ws_size >= need8) ? 1 : 0;
    int NC = priv ? NXCD : 1;

    unsigned* deg_priv = (unsigned*)d_ws;
    float*    out_priv = (float*)(deg_priv + (size_t)NC * n);
    float*    norm_out = out_priv + (size_t)NC * n * FEAT_OUT;
    float*    norm_in  = norm_out + n;
    float*    feat     = norm_in + n;

    hipMemsetAsync(d_ws, 0, (size_t)NC * n * 4 * (1 + FEAT_OUT), stream);

    degree_kernel<<<4096, 256, 0, stream>>>(src, dst, deg_priv, E, n, priv);
    norm_kernel<<<(n + 255) / 256, 256, 0, stream>>>(deg_priv, norm_out, norm_in, n, NC);
    feat_kernel<<<2048, 256, 0, stream>>>(h, W, norm_out, feat, n);
    scatter_kernel<<<4096, 256, 0, stream>>>(src, dst, feat, out_priv, E, n, priv);
    final_kernel<<<(n + 255) / 256, 256, 0, stream>>>(out_priv, norm_in, b, out, n, NC);
}

// Round 3
// 328.105 us; speedup vs baseline: 4.3933x; 1.0370x over previous
//
#include <hip/hip_runtime.h>

#define FEAT_IN  500
#define FEAT_OUT 7
#define NXCD     8
#define OVF_CAP  65536

// ---- partition path params ----
#define RNG     512          // nodes per coarse bucket
#define LG      9            // log2(RNG)
#define NB_MAX  256          // max coarse buckets (n <= 131072)
#define OVF_D   16384
#define OVF_S   65536
#define NBLK1   1024         // partition blocks
#define CH_S    4            // srccount chunks per bucket

// ============================================================================
// PRIMARY PATH: block-aggregated two-level partition (round-2) + CHUNKED
// accumulate/histogram (round-3). Round-2's accum was latency-starved at 392
// blocks / 24% occupancy; chunking to nb*CH_A blocks with staged partials
// restores occupancy with zero added global atomics.
// ============================================================================

__global__ void init_kernel(unsigned long long* __restrict__ gcur,
                            unsigned* __restrict__ ovfc, int nb, int cap) {
    int i = blockIdx.x * blockDim.x + threadIdx.x;
    if (i < nb) {
        unsigned long long v = (unsigned long long)(unsigned)(i * cap);
        gcur[i] = (v << 32) | v;   // high: src cursor, low: dst cursor
    }
    if (i < 16) ovfc[i] = 0;
}

// P1: partition edges into coarse dst-buckets (packed u32) and src-buckets (u16
// local id). Per-block LDS histogram, one u64 global atomic per (block,bucket).
__global__ void partition_kernel(const int* __restrict__ src, const int* __restrict__ dst,
                                 unsigned long long* __restrict__ gcur,
                                 unsigned* __restrict__ dstpart, unsigned short* __restrict__ srcpart,
                                 unsigned* __restrict__ ovfc, unsigned* __restrict__ ovf_d,
                                 unsigned* __restrict__ ovf_s, int E, int nb, int cap) {
    __shared__ unsigned cd[NB_MAX], cs[NB_MAX], sd[NB_MAX], ss[NB_MAX];
    int chunk = (E + gridDim.x - 1) / gridDim.x;
    int e0 = blockIdx.x * chunk;
    int e1 = min(e0 + chunk, E);

    for (int i = threadIdx.x; i < nb; i += blockDim.x) { cd[i] = 0; cs[i] = 0; }
    __syncthreads();

    for (int e = e0 + threadIdx.x; e < e1; e += blockDim.x) {
        atomicAdd(&cd[dst[e] >> LG], 1u);
        atomicAdd(&cs[src[e] >> LG], 1u);
    }
    __syncthreads();

    for (int i = threadIdx.x; i < nb; i += blockDim.x) {
        unsigned long long pk = ((unsigned long long)cs[i] << 32) | (unsigned long long)cd[i];
        unsigned long long old = atomicAdd(&gcur[i], pk);   // one atomic reserves BOTH ranges
        sd[i] = (unsigned)old;
        ss[i] = (unsigned)(old >> 32);
        cd[i] = 0; cs[i] = 0;       // reuse as block-local cursors
    }
    __syncthreads();

    for (int e = e0 + threadIdx.x; e < e1; e += blockDim.x) {
        int s = src[e], d = dst[e];
        int bd = d >> LG, bs = s >> LG;
        unsigned pd = sd[bd] + atomicAdd(&cd[bd], 1u);
        if (pd < (unsigned)((bd + 1) * cap)) {
            dstpart[pd] = ((unsigned)(d & (RNG - 1)) << 17) | (unsigned)s;
        } else {
            unsigned o = atomicAdd(&ovfc[0], 1u);
            if (o < OVF_D) { ovf_d[2 * o] = (unsigned)s; ovf_d[2 * o + 1] = (unsigned)d; }
        }
        unsigned ps = ss[bs] + atomicAdd(&cs[bs], 1u);
        if (ps < (unsigned)((bs + 1) * cap)) {
            srcpart[ps] = (unsigned short)(s & (RNG - 1));
        } else {
            unsigned o = atomicAdd(&ovfc[1], 1u);
            if (o < OVF_S) ovf_s[o] = (unsigned)s;
        }
    }
}

// P2b: chunked out-degree histogram. Block (b,ch): 512-bin LDS hist over its
// slice of srcpart[b], staged to outcnt_c[ch]. 256 threads.
__global__ void srccount_kernel(const unsigned long long* __restrict__ gcur,
                                const unsigned short* __restrict__ srcpart,
                                unsigned* __restrict__ outcnt_c, int cap, int npad, int chs) {
    int b = blockIdx.x / chs, ch = blockIdx.x % chs;
    __shared__ unsigned hist[RNG];
    hist[threadIdx.x] = 0;
    hist[threadIdx.x + 256] = 0;
    __syncthreads();
    unsigned base = (unsigned)b * (unsigned)cap;
    unsigned tot = (unsigned)(gcur[b] >> 32) - base;
    unsigned scnt = tot < (unsigned)cap ? tot : (unsigned)cap;
    unsigned clen = (scnt + (unsigned)chs - 1) / (unsigned)chs;
    unsigned i0 = (unsigned)ch * clen;
    unsigned i1 = i0 + clen; if (i1 > scnt) i1 = scnt;
    for (unsigned i = i0 + threadIdx.x; i < i1; i += blockDim.x)
        atomicAdd(&hist[srcpart[base + i]], 1u);
    __syncthreads();
    unsigned* oc = outcnt_c + (size_t)ch * npad + (size_t)b * RNG;
    oc[threadIdx.x] = hist[threadIdx.x];
    oc[threadIdx.x + 256] = hist[threadIdx.x + 256];
}

__global__ void red_outcnt_kernel(const unsigned* __restrict__ outcnt_c,
                                  unsigned* __restrict__ outcnt, int npad, int chs) {
    int i = blockIdx.x * blockDim.x + threadIdx.x;
    if (i < npad) {
        unsigned s = 0;
        for (int c = 0; c < chs; ++c) s += outcnt_c[(size_t)c * npad + i];
        outcnt[i] = s;
    }
}

__global__ void ovf_s_kernel(const unsigned* __restrict__ ovfc, const unsigned* __restrict__ ovf_s,
                             unsigned* __restrict__ outcnt) {
    unsigned c = ovfc[1]; if (c > OVF_S) c = OVF_S;
    unsigned stride = gridDim.x * blockDim.x;
    for (unsigned i = blockIdx.x * blockDim.x + threadIdx.x; i < c; i += stride)
        atomicAdd(&outcnt[ovf_s[i]], 1u);
}

// P2a: chunked accumulate. Block (b,ch): full 512-node LDS accumulator
// (stride-9 pad), its slice of dstpart[b], partials staged to accf_c[ch].
// 512 threads, 18.4 KB LDS -> ~full occupancy at nb*cha blocks.
__global__ void accum_kernel(const unsigned long long* __restrict__ gcur,
                             const unsigned* __restrict__ dstpart,
                             const float* __restrict__ feat,
                             float* __restrict__ accf_c, int cap, int npad, int cha) {
    int b = blockIdx.x / cha, ch = blockIdx.x % cha;
    __shared__ float acc[RNG * 9];
    for (int i = threadIdx.x; i < RNG * 9; i += blockDim.x) acc[i] = 0.f;
    __syncthreads();
    unsigned base = (unsigned)b * (unsigned)cap;
    unsigned tot = (unsigned)(gcur[b] & 0xffffffffu) - base;
    unsigned ecnt = tot < (unsigned)cap ? tot : (unsigned)cap;
    unsigned clen = (ecnt + (unsigned)cha - 1) / (unsigned)cha;
    unsigned i0 = (unsigned)ch * clen;
    unsigned i1 = i0 + clen; if (i1 > ecnt) i1 = ecnt;
    for (unsigned i = i0 + threadIdx.x; i < i1; i += blockDim.x) {
        unsigned pk = dstpart[base + i];
        unsigned dl = pk >> 17;
        const float4* f = (const float4*)(feat + (size_t)(pk & 0x1FFFFu) * 8);
        float4 a = f[0], c = f[1];
        float* p = acc + dl * 9;
        atomicAdd(p + 0, a.x); atomicAdd(p + 1, a.y); atomicAdd(p + 2, a.z); atomicAdd(p + 3, a.w);
        atomicAdd(p + 4, c.x); atomicAdd(p + 5, c.y); atomicAdd(p + 6, c.z); atomicAdd(p + 7, 1.0f);
    }
    __syncthreads();
    float* dstp = accf_c + (size_t)ch * npad * 8 + (size_t)b * (RNG * 8);
    for (int i2 = threadIdx.x; i2 < RNG * 8; i2 += blockDim.x)
        dstp[i2] = acc[(i2 >> 3) * 9 + (i2 & 7)];
}

// Overflow cleanup: adds into chunk-0 staging (runs after accum, before final2).
__global__ void ovf_d_kernel(const unsigned* __restrict__ ovfc, const unsigned* __restrict__ ovf_d,
                             const float* __restrict__ feat, float* __restrict__ accf_c) {
    unsigned c = ovfc[0]; if (c > OVF_D) c = OVF_D;
    unsigned stride = gridDim.x * blockDim.x;
    for (unsigned i = blockIdx.x * blockDim.x + threadIdx.x; i < c; i += stride) {
        unsigned s = ovf_d[2 * i], d = ovf_d[2 * i + 1];
        const float* f = feat + (size_t)s * 8;
        float* p = accf_c + (size_t)d * 8;
        #pragma unroll
        for (int j = 0; j < FEAT_OUT; ++j) atomicAdd(p + j, f[j]);
        atomicAdd(p + 7, 1.0f);
    }
}

// Final: reduce cha staged copies, apply norm_in (from slot 7 count) + bias.
__global__ void final2_kernel(const float* __restrict__ accf_c, const float* __restrict__ b,
                              float* __restrict__ out, int n, int npad, int cha) {
    int i = blockIdx.x * blockDim.x + threadIdx.x;
    if (i >= n) return;
    float s0 = 0, s1 = 0, s2 = 0, s3 = 0, s4 = 0, s5 = 0, s6 = 0, s7 = 0;
    for (int c = 0; c < cha; ++c) {
        const float4* p = (const float4*)(accf_c + (size_t)c * npad * 8 + (size_t)i * 8);
        float4 a = p[0], d = p[1];
        s0 += a.x; s1 += a.y; s2 += a.z; s3 += a.w;
        s4 += d.x; s5 += d.y; s6 += d.z; s7 += d.w;
    }
    float nin = rsqrtf(fmaxf(s7, 1.0f));
    float* o = out + (size_t)i * FEAT_OUT;
    o[0] = s0 * nin + b[0]; o[1] = s1 * nin + b[1]; o[2] = s2 * nin + b[2];
    o[3] = s3 * nin + b[3]; o[4] = s4 * nin + b[4]; o[5] = s5 * nin + b[5];
    o[6] = s6 * nin + b[6];
}

// K2: feat = (h @ W) * norm_out, padded row stride 8. norm_out fused from outcnt.
__global__ void feat_kernel2(const float* __restrict__ h, const float* __restrict__ W,
                             const unsigned* __restrict__ outcnt,
                             float* __restrict__ feat, int n) {
    __shared__ float Wt[FEAT_OUT * FEAT_IN];  // 14 KB, transposed
    for (int k = threadIdx.x; k < FEAT_IN; k += blockDim.x) {
        #pragma unroll
        for (int j = 0; j < FEAT_OUT; ++j) Wt[j * FEAT_IN + k] = W[k * FEAT_OUT + j];
    }
    __syncthreads();

    const int lane   = threadIdx.x & 63;
    const int wid    = (blockIdx.x * blockDim.x + threadIdx.x) >> 6;
    const int nwaves = (gridDim.x * blockDim.x) >> 6;
    const float4* Wt4 = (const float4*)Wt;  // Wt4[j*125 + v]

    for (int i = wid; i < n; i += nwaves) {
        const float4* hv = (const float4*)(h + (size_t)i * FEAT_IN);  // 125 float4s
        float acc[FEAT_OUT] = {0, 0, 0, 0, 0, 0, 0};
        #pragma unroll
        for (int it = 0; it < 2; ++it) {
            int v = it * 64 + lane;
            if (v < 125) {
                float4 x = hv[v];
                #pragma unroll
                for (int j = 0; j < FEAT_OUT; ++j) {
                    float4 w = Wt4[j * 125 + v];
                    acc[j] += x.x * w.x + x.y * w.y + x.z * w.z + x.w * w.w;
                }
            }
        }
        #pragma unroll
        for (int j = 0; j < FEAT_OUT; ++j) {
            #pragma unroll
            for (int o = 32; o > 0; o >>= 1) acc[j] += __shfl_xor(acc[j], o, 64);
        }
        if (lane == 0) {
            float nrm = rsqrtf(fmaxf((float)outcnt[i], 1.0f));
            float* fo = feat + (size_t)i * 8;
            #pragma unroll
            for (int j = 0; j < FEAT_OUT; ++j) fo[j] = acc[j] * nrm;
        }
    }
}

// ============================================================================
// SECONDARY PATH (round-1 verified): per-edge counting-sort buckets + gather.
// ============================================================================

__global__ void count_scatter_kernel(const int* __restrict__ src, const int* __restrict__ dst,
                                     unsigned* __restrict__ cursor, unsigned* __restrict__ outcnt,
                                     unsigned* __restrict__ bucket, unsigned* __restrict__ ovfcnt,
                                     unsigned* __restrict__ ovf, int E, int cap) {
    int stride = gridDim.x * blockDim.x;
    for (int e = blockIdx.x * blockDim.x + threadIdx.x; e < E; e += stride) {
        int s = src[e], d = dst[e];
        atomicAdd(&outcnt[s], 1u);
        unsigned pos = atomicAdd(&cursor[d], 1u);
        if (pos < (unsigned)cap) {
            bucket[(size_t)d * cap + pos] = (unsigned)s;
        } else {
            unsigned o = atomicAdd(ovfcnt, 1u);
            if (o < OVF_CAP) { ovf[2 * o] = (unsigned)s; ovf[2 * o + 1] = (unsigned)d; }
        }
    }
}

__global__ void gather_kernel(const unsigned* __restrict__ cursor, const unsigned* __restrict__ bucket,
                              const float* __restrict__ feat, const float* __restrict__ b,
                              float* __restrict__ out, int n, int cap) {
    int t   = blockIdx.x * blockDim.x + threadIdx.x;
    int gid = t >> 3;
    int l   = t & 7;
    if (gid >= n) return;

    unsigned full = cursor[gid];
    int cnt = (int)(full < (unsigned)cap ? full : (unsigned)cap);
    const unsigned* bk = bucket + (size_t)gid * cap;

    float acc[FEAT_OUT] = {0, 0, 0, 0, 0, 0, 0};
    for (int e = l; e < cnt; e += 8) {
        unsigned s = bk[e];
        const float4* f = (const float4*)(feat + (size_t)s * 8);
        float4 a = f[0];
        float4 c = f[1];
        acc[0] += a.x; acc[1] += a.y; acc[2] += a.z; acc[3] += a.w;
        acc[4] += c.x; acc[5] += c.y; acc[6] += c.z;
    }
    #pragma unroll
    for (int j = 0; j < FEAT_OUT; ++j) {
        acc[j] += __shfl_xor(acc[j], 1, 64);
        acc[j] += __shfl_xor(acc[j], 2, 64);
        acc[j] += __shfl_xor(acc[j], 4, 64);
    }
    if (l == 0) {
        float nin = rsqrtf(fmaxf((float)full, 1.0f));
        float* o = out + (size_t)gid * FEAT_OUT;
        #pragma unroll
        for (int j = 0; j < FEAT_OUT; ++j) o[j] = acc[j] * nin + b[j];
    }
}

__global__ void ovf_kernel(const unsigned* __restrict__ ovfcnt, const unsigned* __restrict__ ovf,
                           const float* __restrict__ feat, const unsigned* __restrict__ cursor,
                           float* __restrict__ out) {
    unsigned c = ovfcnt[0];
    if (c > OVF_CAP) c = OVF_CAP;
    unsigned stride = gridDim.x * blockDim.x;
    for (unsigned i = blockIdx.x * blockDim.x + threadIdx.x; i < c; i += stride) {
        unsigned s = ovf[2 * i], d = ovf[2 * i + 1];
        float nin = rsqrtf(fmaxf((float)cursor[d], 1.0f));
        const float* f = feat + (size_t)s * 8;
        #pragma unroll
        for (int j = 0; j < FEAT_OUT; ++j)
            atomicAdd(&out[(size_t)d * FEAT_OUT + j], f[j] * nin);
    }
}

// ============================================================================
// TERTIARY PATH (round-0 verified): privatized atomic scatter.
// ============================================================================

__device__ __forceinline__ int xcc_id() {
    int x;
    asm volatile("s_getreg_b32 %0, hwreg(HW_REG_XCC_ID)" : "=s"(x));
    return x & (NXCD - 1);
}

__device__ __forceinline__ void atom_add_f(float* p, float v, int priv) {
    if (priv) __hip_atomic_fetch_add(p, v, __ATOMIC_RELAXED, __HIP_MEMORY_SCOPE_WORKGROUP);
    else      atomicAdd(p, v);
}

__device__ __forceinline__ void atom_add_u(unsigned* p, unsigned v, int priv) {
    if (priv) __hip_atomic_fetch_add(p, v, __ATOMIC_RELAXED, __HIP_MEMORY_SCOPE_WORKGROUP);
    else      atomicAdd(p, v);
}

__global__ void degree_kernel(const int* __restrict__ src, const int* __restrict__ dst,
                              unsigned* __restrict__ deg_priv, int E, int n, int priv) {
    unsigned* deg = deg_priv + (priv ? (size_t)xcc_id() * n : 0);
    int stride = gridDim.x * blockDim.x;
    for (int e = blockIdx.x * blockDim.x + threadIdx.x; e < E; e += stride) {
        atom_add_u(&deg[src[e]], 1u, priv);
        atom_add_u(&deg[dst[e]], 1u << 16, priv);
    }
}

__global__ void norm_kernel(const unsigned* __restrict__ deg_priv,
                            float* __restrict__ norm_out, float* __restrict__ norm_in,
                            int n, int ncopies) {
    int i = blockIdx.x * blockDim.x + threadIdx.x;
    if (i < n) {
        unsigned s = 0;
        for (int x = 0; x < ncopies; ++x) s += deg_priv[(size_t)x * n + i];
        norm_out[i] = rsqrtf(fmaxf((float)(s & 0xffffu), 1.0f));
        norm_in[i]  = rsqrtf(fmaxf((float)(s >> 16), 1.0f));
    }
}

__global__ void feat_kernel(const float* __restrict__ h, const float* __restrict__ W,
                            const float* __restrict__ norm_out,
                            float* __restrict__ feat, int n) {
    __shared__ float Wt[FEAT_OUT * FEAT_IN];
    for (int k = threadIdx.x; k < FEAT_IN; k += blockDim.x) {
        #pragma unroll
        for (int j = 0; j < FEAT_OUT; ++j) Wt[j * FEAT_IN + k] = W[k * FEAT_OUT + j];
    }
    __syncthreads();

    const int lane   = threadIdx.x & 63;
    const int wid    = (blockIdx.x * blockDim.x + threadIdx.x) >> 6;
    const int nwaves = (gridDim.x * blockDim.x) >> 6;
    const float4* Wt4 = (const float4*)Wt;

    for (int i = wid; i < n; i += nwaves) {
        const float4* hv = (const float4*)(h + (size_t)i * FEAT_IN);
        float acc[FEAT_OUT] = {0, 0, 0, 0, 0, 0, 0};
        #pragma unroll
        for (int it = 0; it < 2; ++it) {
            int v = it * 64 + lane;
            if (v < 125) {
                float4 x = hv[v];
                #pragma unroll
                for (int j = 0; j < FEAT_OUT; ++j) {
                    float4 w = Wt4[j * 125 + v];
                    acc[j] += x.x * w.x + x.y * w.y + x.z * w.z + x.w * w.w;
                }
            }
        }
        #pragma unroll
        for (int j = 0; j < FEAT_OUT; ++j) {
            #pragma unroll
            for (int o = 32; o > 0; o >>= 1) acc[j] += __shfl_xor(acc[j], o, 64);
        }
        if (lane == 0) {
            float nrm = norm_out[i];
            float* fo = feat + (size_t)i * 8;
            #pragma unroll
            for (int j = 0; j < FEAT_OUT; ++j) fo[j] = acc[j] * nrm;
        }
    }
}

__global__ void scatter_kernel(const int* __restrict__ src, const int* __restrict__ dst,
                               const float* __restrict__ feat, float* __restrict__ out_priv,
                               int E, int n, int priv) {
    float* out = out_priv + (priv ? (size_t)xcc_id() * ((size_t)n * FEAT_OUT) : 0);
    int stride = gridDim.x * blockDim.x;
    for (int e = blockIdx.x * blockDim.x + threadIdx.x; e < E; e += stride) {
        int s = src[e], d = dst[e];
        const float* f = feat + (size_t)s * 8;
        float4 a = *(const float4*)(f);
        float4 c = *(const float4*)(f + 4);
        float* o = out + (size_t)d * FEAT_OUT;
        atom_add_f(o + 0, a.x, priv);
        atom_add_f(o + 1, a.y, priv);
        atom_add_f(o + 2, a.z, priv);
        atom_add_f(o + 3, a.w, priv);
        atom_add_f(o + 4, c.x, priv);
        atom_add_f(o + 5, c.y, priv);
        atom_add_f(o + 6, c.z, priv);
    }
}

__global__ void final_kernel(const float* __restrict__ out_priv, const float* __restrict__ norm_in,
                             const float* __restrict__ b, float* __restrict__ out,
                             int n, int ncopies) {
    int i = blockIdx.x * blockDim.x + threadIdx.x;
    if (i < n) {
        float acc[FEAT_OUT] = {0, 0, 0, 0, 0, 0, 0};
        for (int x = 0; x < ncopies; ++x) {
            const float* p = out_priv + (size_t)x * n * FEAT_OUT + (size_t)i * FEAT_OUT;
            #pragma unroll
            for (int j = 0; j < FEAT_OUT; ++j) acc[j] += p[j];
        }
        float nin = norm_in[i];
        float* o = out + (size_t)i * FEAT_OUT;
        #pragma unroll
        for (int j = 0; j < FEAT_OUT; ++j) o[j] = acc[j] * nin + b[j];
    }
}

// ============================================================================

extern "C" void kernel_launch(void* const* d_in, const int* in_sizes, int n_in,
                              void* d_out, int out_size, void* d_ws, size_t ws_size,
                              hipStream_t stream) {
    const float* h   = (const float*)d_in[0];
    const float* W   = (const float*)d_in[1];
    const float* b   = (const float*)d_in[2];
    const int*   src = (const int*)d_in[3];
    const int*   dst = (const int*)d_in[4];

    const int n = in_sizes[0] / FEAT_IN;   // 100000
    const int E = in_sizes[3];             // 3300000
    float* out = (float*)d_out;

    // ---------------- primary: partition path (chunked) ----------------
    int nb = (n + RNG - 1) / RNG;          // 196
    if (nb >= 2 && nb <= NB_MAX) {
        size_t npad = (size_t)nb * RNG;
        // cap = mean + ~13 sigma, rounded to 64 (overflow prob ~1e-38/bucket;
        // spills go to ovf lists and are handled exactly anyway).
        long cap = (long)(E / nb) + (long)(E / nb) / 16 + 640;
        cap = (cap + 63) & ~63L;
        if (cap > 65536) cap = 65536;

        // base: gcur | ovfc | ovf_s | ovf_d | feat | dstpart
        // overlay (reused): A-view = outcnt | outcnt_c | srcpart  (all dead
        // before accum runs)  /  B-view = accf_c (written by accum, stream-
        // ordered after every A-view consumer).
        size_t dstpart_sz = (size_t)nb * cap * 4;
        size_t srcpart_sz = (size_t)nb * cap * 2;
        size_t base_off   = 2048 + 64 + (size_t)OVF_S * 4 + (size_t)OVF_D * 8
                          + npad * 32 + dstpart_sz;
        size_t overlayA   = npad * 4 + (size_t)CH_S * npad * 4 + srcpart_sz;

        long cha = 0;
        if (ws_size > base_off) {
            size_t over = ws_size - base_off;
            if (over >= overlayA) {
                cha = (long)(over / (npad * 32));
                if (cha > 8) cha = 8;
            }
        }

        if (cha >= 2) {
            char* p = (char*)d_ws;
            unsigned long long* gcur = (unsigned long long*)p;  p += 2048;
            unsigned* ovfc    = (unsigned*)p;                   p += 64;
            unsigned* ovf_s   = (unsigned*)p;                   p += (size_t)OVF_S * 4;
            unsigned* ovf_d   = (unsigned*)p;                   p += (size_t)OVF_D * 8;
            float*    feat    = (float*)p;                      p += npad * 32;
            unsigned* dstpart = (unsigned*)p;                   p += dstpart_sz;
            char* ov = p;
            unsigned*       outcnt   = (unsigned*)ov;
            unsigned*       outcnt_c = (unsigned*)(ov + npad * 4);
            unsigned short* srcpart  = (unsigned short*)(ov + npad * 4 + (size_t)CH_S * npad * 4);
            float*          accf_c   = (float*)ov;   // overlays A-view

            init_kernel<<<1, 256, 0, stream>>>(gcur, ovfc, nb, (int)cap);
            partition_kernel<<<NBLK1, 256, 0, stream>>>(src, dst, gcur, dstpart, srcpart,
                                                        ovfc, ovf_d, ovf_s, E, nb, (int)cap);
            srccount_kernel<<<nb * CH_S, 256, 0, stream>>>(gcur, srcpart, outcnt_c,
                                                           (int)cap, (int)npad, CH_S);
            red_outcnt_kernel<<<((int)npad + 255) / 256, 256, 0, stream>>>(outcnt_c, outcnt,
                                                                           (int)npad, CH_S);
            ovf_s_kernel<<<4, 256, 0, stream>>>(ovfc, ovf_s, outcnt);
            feat_kernel2<<<2048, 256, 0, stream>>>(h, W, outcnt, feat, n);
            accum_kernel<<<nb * (int)cha, 512, 0, stream>>>(gcur, dstpart, feat, accf_c,
                                                            (int)cap, (int)npad, (int)cha);
            ovf_d_kernel<<<4, 256, 0, stream>>>(ovfc, ovf_d, feat, accf_c);
            final2_kernel<<<(n + 255) / 256, 256, 0, stream>>>(accf_c, b, out, n,
                                                               (int)npad, (int)cha);
            return;
        }
    }

    // ---------------- secondary: round-1 bucket path ----------------
    size_t fixed = (size_t)n * 4 * 2 + 64 + (size_t)n * 8 * 4 + (size_t)OVF_CAP * 8;
    int cap = 0;
    if (ws_size > fixed) cap = (int)((ws_size - fixed) / ((size_t)n * 4));
    if (cap > 96) cap = 96;

    if (cap >= 64) {
        unsigned* cursor = (unsigned*)d_ws;
        unsigned* outcnt = cursor + n;
        unsigned* ovfcnt = outcnt + n;
        float*    feat   = (float*)(ovfcnt + 16);
        unsigned* ovf    = (unsigned*)(feat + (size_t)n * 8);
        unsigned* bucket = ovf + (size_t)OVF_CAP * 2;

        hipMemsetAsync(d_ws, 0, (size_t)n * 8 + 64, stream);

        count_scatter_kernel<<<4096, 256, 0, stream>>>(src, dst, cursor, outcnt, bucket,
                                                       ovfcnt, ovf, E, cap);
        feat_kernel2<<<2048, 256, 0, stream>>>(h, W, outcnt, feat, n);
        gather_kernel<<<((size_t)n * 8 + 255) / 256, 256, 0, stream>>>(cursor, bucket, feat,
                                                                       b, out, n, cap);
        ovf_kernel<<<16, 256, 0, stream>>>(ovfcnt, ovf, feat, cursor, out);
        return;
    }

    // ---------------- tertiary: round-0 atomic path ----------------
    size_t need8 = (size_t)NXCD * n * 4 + (size_t)NXCD * n * FEAT_OUT * 4
                 + (size_t)n * 4 * 2 + (size_t)n * 8 * 4;
    int priv = (ws_size >= need8) ? 1 : 0;
    int NC = priv ? NXCD : 1;

    unsigned* deg_priv = (unsigned*)d_ws;
    float*    out_priv = (float*)(deg_priv + (size_t)NC * n);
    float*    norm_out = out_priv + (size_t)NC * n * FEAT_OUT;
    float*    norm_in  = norm_out + n;
    float*    feat     = norm_in + n;

    hipMemsetAsync(d_ws, 0, (size_t)NC * n * 4 * (1 + FEAT_OUT), stream);

    degree_kernel<<<4096, 256, 0, stream>>>(src, dst, deg_priv, E, n, priv);
    norm_kernel<<<(n + 255) / 256, 256, 0, stream>>>(deg_priv, norm_out, norm_in, n, NC);
    feat_kernel<<<2048, 256, 0, stream>>>(h, W, norm_out, feat, n);
    scatter_kernel<<<4096, 256, 0, stream>>>(src, dst, feat, out_priv, E, n, priv);
    final_kernel<<<(n + 255) / 256, 256, 0, stream>>>(out_priv, norm_in, b, out, n, NC);
}

// Round 4
// 200.709 us; speedup vs baseline: 7.1819x; 1.6347x over previous
//
#include <hip/hip_runtime.h>

#define FEAT_IN  500
#define FEAT_OUT 7
#define NXCD     8
#define OVF_CAP  65536

// ---- partition path params ----
#define RNG     512          // nodes per coarse bucket
#define LG      9            // log2(RNG)
#define NB_MAX  256          // max coarse buckets (n <= 131072)
#define OVF_D   16384
#define OVF_S   65536
#define NBLK1   1024         // partition blocks
#define CH_S    8            // srccount chunks per bucket
#define SLABN   16           // slab entries per (node,chunk) in accum3
#define SLABS   17           // slab stride (pad vs bank conflicts)

// ============================================================================
// PRIMARY PATH. Measured wall (r3): LDS atomics ~3.7 cyc/lane-atomic
// (0.27/cyc/CU) — runtime ∝ LDS atomics/edge. r3 spent 13/edge
// (partition 4, srccount 1, accum 8). accum3 cuts accum 8 -> 1 via in-LDS
// slab sort + atomic-free register reduce.
// ============================================================================

__global__ void init_kernel(unsigned long long* __restrict__ gcur,
                            unsigned* __restrict__ ovfc, int nb, int cap) {
    int i = blockIdx.x * blockDim.x + threadIdx.x;
    if (i < nb) {
        unsigned long long v = (unsigned long long)(unsigned)(i * cap);
        gcur[i] = (v << 32) | v;   // high: src cursor, low: dst cursor
    }
    if (i < 16) ovfc[i] = 0;
}

// P1: partition edges into coarse dst-buckets (packed u32) and src-buckets (u16
// local id). Per-block LDS histogram, one u64 global atomic per (block,bucket).
// Exact reservation: robust to the sorted self-loop tail.
__global__ void partition_kernel(const int* __restrict__ src, const int* __restrict__ dst,
                                 unsigned long long* __restrict__ gcur,
                                 unsigned* __restrict__ dstpart, unsigned short* __restrict__ srcpart,
                                 unsigned* __restrict__ ovfc, unsigned* __restrict__ ovf_d,
                                 unsigned* __restrict__ ovf_s, int E, int nb, int cap) {
    __shared__ unsigned cd[NB_MAX], cs[NB_MAX], sd[NB_MAX], ss[NB_MAX];
    int chunk = (E + gridDim.x - 1) / gridDim.x;
    int e0 = blockIdx.x * chunk;
    int e1 = min(e0 + chunk, E);

    for (int i = threadIdx.x; i < nb; i += blockDim.x) { cd[i] = 0; cs[i] = 0; }
    __syncthreads();

    for (int e = e0 + threadIdx.x; e < e1; e += blockDim.x) {
        atomicAdd(&cd[dst[e] >> LG], 1u);
        atomicAdd(&cs[src[e] >> LG], 1u);
    }
    __syncthreads();

    for (int i = threadIdx.x; i < nb; i += blockDim.x) {
        unsigned long long pk = ((unsigned long long)cs[i] << 32) | (unsigned long long)cd[i];
        unsigned long long old = atomicAdd(&gcur[i], pk);   // one atomic reserves BOTH ranges
        sd[i] = (unsigned)old;
        ss[i] = (unsigned)(old >> 32);
        cd[i] = 0; cs[i] = 0;       // reuse as block-local cursors
    }
    __syncthreads();

    for (int e = e0 + threadIdx.x; e < e1; e += blockDim.x) {
        int s = src[e], d = dst[e];
        int bd = d >> LG, bs = s >> LG;
        unsigned pd = sd[bd] + atomicAdd(&cd[bd], 1u);
        if (pd < (unsigned)((bd + 1) * cap)) {
            dstpart[pd] = ((unsigned)(d & (RNG - 1)) << 17) | (unsigned)s;
        } else {
            unsigned o = atomicAdd(&ovfc[0], 1u);
            if (o < OVF_D) { ovf_d[2 * o] = (unsigned)s; ovf_d[2 * o + 1] = (unsigned)d; }
        }
        unsigned ps = ss[bs] + atomicAdd(&cs[bs], 1u);
        if (ps < (unsigned)((bs + 1) * cap)) {
            srcpart[ps] = (unsigned short)(s & (RNG - 1));
        } else {
            unsigned o = atomicAdd(&ovfc[1], 1u);
            if (o < OVF_S) ovf_s[o] = (unsigned)s;
        }
    }
}

// P2b: chunked out-degree histogram. Block (b,ch): 512-bin LDS hist over its
// slice of srcpart[b], staged to outcnt_c[ch]. 256 threads.
__global__ void srccount_kernel(const unsigned long long* __restrict__ gcur,
                                const unsigned short* __restrict__ srcpart,
                                unsigned* __restrict__ outcnt_c, int cap, int npad, int chs) {
    int b = blockIdx.x / chs, ch = blockIdx.x % chs;
    __shared__ unsigned hist[RNG];
    hist[threadIdx.x] = 0;
    hist[threadIdx.x + 256] = 0;
    __syncthreads();
    unsigned base = (unsigned)b * (unsigned)cap;
    unsigned tot = (unsigned)(gcur[b] >> 32) - base;
    unsigned scnt = tot < (unsigned)cap ? tot : (unsigned)cap;
    unsigned clen = (scnt + (unsigned)chs - 1) / (unsigned)chs;
    unsigned i0 = (unsigned)ch * clen;
    unsigned i1 = i0 + clen; if (i1 > scnt) i1 = scnt;
    for (unsigned i = i0 + threadIdx.x; i < i1; i += blockDim.x)
        atomicAdd(&hist[srcpart[base + i]], 1u);
    __syncthreads();
    unsigned* oc = outcnt_c + (size_t)ch * npad + (size_t)b * RNG;
    oc[threadIdx.x] = hist[threadIdx.x];
    oc[threadIdx.x + 256] = hist[threadIdx.x + 256];
}

__global__ void red_outcnt_kernel(const unsigned* __restrict__ outcnt_c,
                                  unsigned* __restrict__ outcnt, int npad, int chs) {
    int i = blockIdx.x * blockDim.x + threadIdx.x;
    if (i < npad) {
        unsigned s = 0;
        for (int c = 0; c < chs; ++c) s += outcnt_c[(size_t)c * npad + i];
        outcnt[i] = s;
    }
}

__global__ void ovf_s_kernel(const unsigned* __restrict__ ovfc, const unsigned* __restrict__ ovf_s,
                             unsigned* __restrict__ outcnt) {
    unsigned c = ovfc[1]; if (c > OVF_S) c = OVF_S;
    unsigned stride = gridDim.x * blockDim.x;
    for (unsigned i = blockIdx.x * blockDim.x + threadIdx.x; i < c; i += stride)
        atomicAdd(&outcnt[ovf_s[i]], 1u);
}

// P2a-NEW: slab-sort accumulate, 1 LDS atomic/edge. Block (b,ch):
// phase1: each edge -> cur[dl]++ (LDS) + plain LDS write of src into node slab;
// phase2: thread t reduces node t's slab in REGISTERS (0 atomics), writes
// 32B partial (+count in slot 7) with plain coalesced stores.
// Slab overflow (P ~ 1e-6 per node-chunk) spills exactly to ovf_d.
__global__ void accum3_kernel(const unsigned long long* __restrict__ gcur,
                              const unsigned* __restrict__ dstpart,
                              const float* __restrict__ feat,
                              float* __restrict__ accf_c,
                              unsigned* __restrict__ ovfc, unsigned* __restrict__ ovf_d,
                              int cap, int npad, int cha) {
    int b = blockIdx.x / cha, ch = blockIdx.x % cha;
    __shared__ unsigned slab[RNG * SLABS];   // 34.8 KB
    __shared__ unsigned cur[RNG];            // 2 KB
    cur[threadIdx.x] = 0;                    // blockDim == RNG == 512
    __syncthreads();
    unsigned base = (unsigned)b * (unsigned)cap;
    unsigned tot = (unsigned)(gcur[b] & 0xffffffffu) - base;
    unsigned ecnt = tot < (unsigned)cap ? tot : (unsigned)cap;
    unsigned clen = (ecnt + (unsigned)cha - 1) / (unsigned)cha;
    unsigned i0 = (unsigned)ch * clen;
    unsigned i1 = i0 + clen; if (i1 > ecnt) i1 = ecnt;
    for (unsigned i = i0 + threadIdx.x; i < i1; i += blockDim.x) {
        unsigned pk = dstpart[base + i];
        unsigned dl = pk >> 17;
        unsigned p = atomicAdd(&cur[dl], 1u);
        if (p < (unsigned)SLABN) {
            slab[dl * SLABS + p] = pk & 0x1FFFFu;
        } else {
            unsigned o = atomicAdd(&ovfc[0], 1u);
            if (o < OVF_D) { ovf_d[2 * o] = pk & 0x1FFFFu; ovf_d[2 * o + 1] = (unsigned)b * RNG + dl; }
        }
    }
    __syncthreads();
    int t = threadIdx.x;
    unsigned cnt = cur[t]; if (cnt > (unsigned)SLABN) cnt = (unsigned)SLABN;
    float a0 = 0, a1 = 0, a2 = 0, a3 = 0, a4 = 0, a5 = 0, a6 = 0;
    const unsigned* sl = slab + t * SLABS;
    for (unsigned k = 0; k < cnt; ++k) {
        const float4* f = (const float4*)(feat + (size_t)sl[k] * 8);
        float4 x = f[0], y = f[1];
        a0 += x.x; a1 += x.y; a2 += x.z; a3 += x.w;
        a4 += y.x; a5 += y.y; a6 += y.z;
    }
    float4* dstp = (float4*)(accf_c + (size_t)ch * npad * 8 + ((size_t)b * RNG + t) * 8);
    dstp[0] = make_float4(a0, a1, a2, a3);
    dstp[1] = make_float4(a4, a5, a6, (float)cnt);
}

// P2a-OLD (r3 fallback for cha<8): LDS float-atomic accumulate.
__global__ void accum_kernel(const unsigned long long* __restrict__ gcur,
                             const unsigned* __restrict__ dstpart,
                             const float* __restrict__ feat,
                             float* __restrict__ accf_c, int cap, int npad, int cha) {
    int b = blockIdx.x / cha, ch = blockIdx.x % cha;
    __shared__ float acc[RNG * 9];
    for (int i = threadIdx.x; i < RNG * 9; i += blockDim.x) acc[i] = 0.f;
    __syncthreads();
    unsigned base = (unsigned)b * (unsigned)cap;
    unsigned tot = (unsigned)(gcur[b] & 0xffffffffu) - base;
    unsigned ecnt = tot < (unsigned)cap ? tot : (unsigned)cap;
    unsigned clen = (ecnt + (unsigned)cha - 1) / (unsigned)cha;
    unsigned i0 = (unsigned)ch * clen;
    unsigned i1 = i0 + clen; if (i1 > ecnt) i1 = ecnt;
    for (unsigned i = i0 + threadIdx.x; i < i1; i += blockDim.x) {
        unsigned pk = dstpart[base + i];
        unsigned dl = pk >> 17;
        const float4* f = (const float4*)(feat + (size_t)(pk & 0x1FFFFu) * 8);
        float4 a = f[0], c = f[1];
        float* p = acc + dl * 9;
        atomicAdd(p + 0, a.x); atomicAdd(p + 1, a.y); atomicAdd(p + 2, a.z); atomicAdd(p + 3, a.w);
        atomicAdd(p + 4, c.x); atomicAdd(p + 5, c.y); atomicAdd(p + 6, c.z); atomicAdd(p + 7, 1.0f);
    }
    __syncthreads();
    float* dstp = accf_c + (size_t)ch * npad * 8 + (size_t)b * (RNG * 8);
    for (int i2 = threadIdx.x; i2 < RNG * 8; i2 += blockDim.x)
        dstp[i2] = acc[(i2 >> 3) * 9 + (i2 & 7)];
}

// Overflow cleanup: adds into chunk-0 staging (after accum, before final2).
__global__ void ovf_d_kernel(const unsigned* __restrict__ ovfc, const unsigned* __restrict__ ovf_d,
                             const float* __restrict__ feat, float* __restrict__ accf_c) {
    unsigned c = ovfc[0]; if (c > OVF_D) c = OVF_D;
    unsigned stride = gridDim.x * blockDim.x;
    for (unsigned i = blockIdx.x * blockDim.x + threadIdx.x; i < c; i += stride) {
        unsigned s = ovf_d[2 * i], d = ovf_d[2 * i + 1];
        const float* f = feat + (size_t)s * 8;
        float* p = accf_c + (size_t)d * 8;
        #pragma unroll
        for (int j = 0; j < FEAT_OUT; ++j) atomicAdd(p + j, f[j]);
        atomicAdd(p + 7, 1.0f);
    }
}

// Final: reduce cha staged copies, apply norm_in (from slot 7 count) + bias.
__global__ void final2_kernel(const float* __restrict__ accf_c, const float* __restrict__ b,
                              float* __restrict__ out, int n, int npad, int cha) {
    int i = blockIdx.x * blockDim.x + threadIdx.x;
    if (i >= n) return;
    float s0 = 0, s1 = 0, s2 = 0, s3 = 0, s4 = 0, s5 = 0, s6 = 0, s7 = 0;
    for (int c = 0; c < cha; ++c) {
        const float4* p = (const float4*)(accf_c + (size_t)c * npad * 8 + (size_t)i * 8);
        float4 a = p[0], d = p[1];
        s0 += a.x; s1 += a.y; s2 += a.z; s3 += a.w;
        s4 += d.x; s5 += d.y; s6 += d.z; s7 += d.w;
    }
    float nin = rsqrtf(fmaxf(s7, 1.0f));
    float* o = out + (size_t)i * FEAT_OUT;
    o[0] = s0 * nin + b[0]; o[1] = s1 * nin + b[1]; o[2] = s2 * nin + b[2];
    o[3] = s3 * nin + b[3]; o[4] = s4 * nin + b[4]; o[5] = s5 * nin + b[5];
    o[6] = s6 * nin + b[6];
}

// K2: feat = (h @ W) * norm_out, padded row stride 8. norm_out fused from outcnt.
__global__ void feat_kernel2(const float* __restrict__ h, const float* __restrict__ W,
                             const unsigned* __restrict__ outcnt,
                             float* __restrict__ feat, int n) {
    __shared__ float Wt[FEAT_OUT * FEAT_IN];  // 14 KB, transposed
    for (int k = threadIdx.x; k < FEAT_IN; k += blockDim.x) {
        #pragma unroll
        for (int j = 0; j < FEAT_OUT; ++j) Wt[j * FEAT_IN + k] = W[k * FEAT_OUT + j];
    }
    __syncthreads();

    const int lane   = threadIdx.x & 63;
    const int wid    = (blockIdx.x * blockDim.x + threadIdx.x) >> 6;
    const int nwaves = (gridDim.x * blockDim.x) >> 6;
    const float4* Wt4 = (const float4*)Wt;  // Wt4[j*125 + v]

    for (int i = wid; i < n; i += nwaves) {
        const float4* hv = (const float4*)(h + (size_t)i * FEAT_IN);  // 125 float4s
        float acc[FEAT_OUT] = {0, 0, 0, 0, 0, 0, 0};
        #pragma unroll
        for (int it = 0; it < 2; ++it) {
            int v = it * 64 + lane;
            if (v < 125) {
                float4 x = hv[v];
                #pragma unroll
                for (int j = 0; j < FEAT_OUT; ++j) {
                    float4 w = Wt4[j * 125 + v];
                    acc[j] += x.x * w.x + x.y * w.y + x.z * w.z + x.w * w.w;
                }
            }
        }
        #pragma unroll
        for (int j = 0; j < FEAT_OUT; ++j) {
            #pragma unroll
            for (int o = 32; o > 0; o >>= 1) acc[j] += __shfl_xor(acc[j], o, 64);
        }
        if (lane == 0) {
            float nrm = rsqrtf(fmaxf((float)outcnt[i], 1.0f));
            float* fo = feat + (size_t)i * 8;
            #pragma unroll
            for (int j = 0; j < FEAT_OUT; ++j) fo[j] = acc[j] * nrm;
        }
    }
}

// ============================================================================
// SECONDARY PATH (round-1 verified): per-edge counting-sort buckets + gather.
// ============================================================================

__global__ void count_scatter_kernel(const int* __restrict__ src, const int* __restrict__ dst,
                                     unsigned* __restrict__ cursor, unsigned* __restrict__ outcnt,
                                     unsigned* __restrict__ bucket, unsigned* __restrict__ ovfcnt,
                                     unsigned* __restrict__ ovf, int E, int cap) {
    int stride = gridDim.x * blockDim.x;
    for (int e = blockIdx.x * blockDim.x + threadIdx.x; e < E; e += stride) {
        int s = src[e], d = dst[e];
        atomicAdd(&outcnt[s], 1u);
        unsigned pos = atomicAdd(&cursor[d], 1u);
        if (pos < (unsigned)cap) {
            bucket[(size_t)d * cap + pos] = (unsigned)s;
        } else {
            unsigned o = atomicAdd(ovfcnt, 1u);
            if (o < OVF_CAP) { ovf[2 * o] = (unsigned)s; ovf[2 * o + 1] = (unsigned)d; }
        }
    }
}

__global__ void gather_kernel(const unsigned* __restrict__ cursor, const unsigned* __restrict__ bucket,
                              const float* __restrict__ feat, const float* __restrict__ b,
                              float* __restrict__ out, int n, int cap) {
    int t   = blockIdx.x * blockDim.x + threadIdx.x;
    int gid = t >> 3;
    int l   = t & 7;
    if (gid >= n) return;

    unsigned full = cursor[gid];
    int cnt = (int)(full < (unsigned)cap ? full : (unsigned)cap);
    const unsigned* bk = bucket + (size_t)gid * cap;

    float acc[FEAT_OUT] = {0, 0, 0, 0, 0, 0, 0};
    for (int e = l; e < cnt; e += 8) {
        unsigned s = bk[e];
        const float4* f = (const float4*)(feat + (size_t)s * 8);
        float4 a = f[0];
        float4 c = f[1];
        acc[0] += a.x; acc[1] += a.y; acc[2] += a.z; acc[3] += a.w;
        acc[4] += c.x; acc[5] += c.y; acc[6] += c.z;
    }
    #pragma unroll
    for (int j = 0; j < FEAT_OUT; ++j) {
        acc[j] += __shfl_xor(acc[j], 1, 64);
        acc[j] += __shfl_xor(acc[j], 2, 64);
        acc[j] += __shfl_xor(acc[j], 4, 64);
    }
    if (l == 0) {
        float nin = rsqrtf(fmaxf((float)full, 1.0f));
        float* o = out + (size_t)gid * FEAT_OUT;
        #pragma unroll
        for (int j = 0; j < FEAT_OUT; ++j) o[j] = acc[j] * nin + b[j];
    }
}

__global__ void ovf_kernel(const unsigned* __restrict__ ovfcnt, const unsigned* __restrict__ ovf,
                           const float* __restrict__ feat, const unsigned* __restrict__ cursor,
                           float* __restrict__ out) {
    unsigned c = ovfcnt[0];
    if (c > OVF_CAP) c = OVF_CAP;
    unsigned stride = gridDim.x * blockDim.x;
    for (unsigned i = blockIdx.x * blockDim.x + threadIdx.x; i < c; i += stride) {
        unsigned s = ovf[2 * i], d = ovf[2 * i + 1];
        float nin = rsqrtf(fmaxf((float)cursor[d], 1.0f));
        const float* f = feat + (size_t)s * 8;
        #pragma unroll
        for (int j = 0; j < FEAT_OUT; ++j)
            atomicAdd(&out[(size_t)d * FEAT_OUT + j], f[j] * nin);
    }
}

// ============================================================================
// TERTIARY PATH (round-0 verified): privatized atomic scatter.
// ============================================================================

__device__ __forceinline__ int xcc_id() {
    int x;
    asm volatile("s_getreg_b32 %0, hwreg(HW_REG_XCC_ID)" : "=s"(x));
    return x & (NXCD - 1);
}

__device__ __forceinline__ void atom_add_f(float* p, float v, int priv) {
    if (priv) __hip_atomic_fetch_add(p, v, __ATOMIC_RELAXED, __HIP_MEMORY_SCOPE_WORKGROUP);
    else      atomicAdd(p, v);
}

__device__ __forceinline__ void atom_add_u(unsigned* p, unsigned v, int priv) {
    if (priv) __hip_atomic_fetch_add(p, v, __ATOMIC_RELAXED, __HIP_MEMORY_SCOPE_WORKGROUP);
    else      atomicAdd(p, v);
}

__global__ void degree_kernel(const int* __restrict__ src, const int* __restrict__ dst,
                              unsigned* __restrict__ deg_priv, int E, int n, int priv) {
    unsigned* deg = deg_priv + (priv ? (size_t)xcc_id() * n : 0);
    int stride = gridDim.x * blockDim.x;
    for (int e = blockIdx.x * blockDim.x + threadIdx.x; e < E; e += stride) {
        atom_add_u(&deg[src[e]], 1u, priv);
        atom_add_u(&deg[dst[e]], 1u << 16, priv);
    }
}

__global__ void norm_kernel(const unsigned* __restrict__ deg_priv,
                            float* __restrict__ norm_out, float* __restrict__ norm_in,
                            int n, int ncopies) {
    int i = blockIdx.x * blockDim.x + threadIdx.x;
    if (i < n) {
        unsigned s = 0;
        for (int x = 0; x < ncopies; ++x) s += deg_priv[(size_t)x * n + i];
        norm_out[i] = rsqrtf(fmaxf((float)(s & 0xffffu), 1.0f));
        norm_in[i]  = rsqrtf(fmaxf((float)(s >> 16), 1.0f));
    }
}

__global__ void feat_kernel(const float* __restrict__ h, const float* __restrict__ W,
                            const float* __restrict__ norm_out,
                            float* __restrict__ feat, int n) {
    __shared__ float Wt[FEAT_OUT * FEAT_IN];
    for (int k = threadIdx.x; k < FEAT_IN; k += blockDim.x) {
        #pragma unroll
        for (int j = 0; j < FEAT_OUT; ++j) Wt[j * FEAT_IN + k] = W[k * FEAT_OUT + j];
    }
    __syncthreads();

    const int lane   = threadIdx.x & 63;
    const int wid    = (blockIdx.x * blockDim.x + threadIdx.x) >> 6;
    const int nwaves = (gridDim.x * blockDim.x) >> 6;
    const float4* Wt4 = (const float4*)Wt;

    for (int i = wid; i < n; i += nwaves) {
        const float4* hv = (const float4*)(h + (size_t)i * FEAT_IN);
        float acc[FEAT_OUT] = {0, 0, 0, 0, 0, 0, 0};
        #pragma unroll
        for (int it = 0; it < 2; ++it) {
            int v = it * 64 + lane;
            if (v < 125) {
                float4 x = hv[v];
                #pragma unroll
                for (int j = 0; j < FEAT_OUT; ++j) {
                    float4 w = Wt4[j * 125 + v];
                    acc[j] += x.x * w.x + x.y * w.y + x.z * w.z + x.w * w.w;
                }
            }
        }
        #pragma unroll
        for (int j = 0; j < FEAT_OUT; ++j) {
            #pragma unroll
            for (int o = 32; o > 0; o >>= 1) acc[j] += __shfl_xor(acc[j], o, 64);
        }
        if (lane == 0) {
            float nrm = norm_out[i];
            float* fo = feat + (size_t)i * 8;
            #pragma unroll
            for (int j = 0; j < FEAT_OUT; ++j) fo[j] = acc[j] * nrm;
        }
    }
}

__global__ void scatter_kernel(const int* __restrict__ src, const int* __restrict__ dst,
                               const float* __restrict__ feat, float* __restrict__ out_priv,
                               int E, int n, int priv) {
    float* out = out_priv + (priv ? (size_t)xcc_id() * ((size_t)n * FEAT_OUT) : 0);
    int stride = gridDim.x * blockDim.x;
    for (int e = blockIdx.x * blockDim.x + threadIdx.x; e < E; e += stride) {
        int s = src[e], d = dst[e];
        const float* f = feat + (size_t)s * 8;
        float4 a = *(const float4*)(f);
        float4 c = *(const float4*)(f + 4);
        float* o = out + (size_t)d * FEAT_OUT;
        atom_add_f(o + 0, a.x, priv);
        atom_add_f(o + 1, a.y, priv);
        atom_add_f(o + 2, a.z, priv);
        atom_add_f(o + 3, a.w, priv);
        atom_add_f(o + 4, c.x, priv);
        atom_add_f(o + 5, c.y, priv);
        atom_add_f(o + 6, c.z, priv);
    }
}

__global__ void final_kernel(const float* __restrict__ out_priv, const float* __restrict__ norm_in,
                             const float* __restrict__ b, float* __restrict__ out,
                             int n, int ncopies) {
    int i = blockIdx.x * blockDim.x + threadIdx.x;
    if (i < n) {
        float acc[FEAT_OUT] = {0, 0, 0, 0, 0, 0, 0};
        for (int x = 0; x < ncopies; ++x) {
            const float* p = out_priv + (size_t)x * n * FEAT_OUT + (size_t)i * FEAT_OUT;
            #pragma unroll
            for (int j = 0; j < FEAT_OUT; ++j) acc[j] += p[j];
        }
        float nin = norm_in[i];
        float* o = out + (size_t)i * FEAT_OUT;
        #pragma unroll
        for (int j = 0; j < FEAT_OUT; ++j) o[j] = acc[j] * nin + b[j];
    }
}

// ============================================================================

extern "C" void kernel_launch(void* const* d_in, const int* in_sizes, int n_in,
                              void* d_out, int out_size, void* d_ws, size_t ws_size,
                              hipStream_t stream) {
    const float* h   = (const float*)d_in[0];
    const float* W   = (const float*)d_in[1];
    const float* b   = (const float*)d_in[2];
    const int*   src = (const int*)d_in[3];
    const int*   dst = (const int*)d_in[4];

    const int n = in_sizes[0] / FEAT_IN;   // 100000
    const int E = in_sizes[3];             // 3300000
    float* out = (float*)d_out;

    // ---------------- primary: partition path (chunked) ----------------
    int nb = (n + RNG - 1) / RNG;          // 196
    if (nb >= 2 && nb <= NB_MAX) {
        size_t npad = (size_t)nb * RNG;
        long cap = (long)(E / nb) + (long)(E / nb) / 16 + 640;
        cap = (cap + 63) & ~63L;
        if (cap > 65536) cap = 65536;

        size_t dstpart_sz = (size_t)nb * cap * 4;
        size_t srcpart_sz = (size_t)nb * cap * 2;
        size_t base_off   = 2048 + 64 + (size_t)OVF_S * 4 + (size_t)OVF_D * 8
                          + npad * 32 + dstpart_sz;
        size_t overlayA   = npad * 4 + (size_t)CH_S * npad * 4 + srcpart_sz;

        long cha = 0;
        if (ws_size > base_off) {
            size_t over = ws_size - base_off;
            if (over >= overlayA) {
                cha = (long)(over / (npad * 32));
                if (cha > 8) cha = 8;
            }
        }

        if (cha >= 2) {
            char* p = (char*)d_ws;
            unsigned long long* gcur = (unsigned long long*)p;  p += 2048;
            unsigned* ovfc    = (unsigned*)p;                   p += 64;
            unsigned* ovf_s   = (unsigned*)p;                   p += (size_t)OVF_S * 4;
            unsigned* ovf_d   = (unsigned*)p;                   p += (size_t)OVF_D * 8;
            float*    feat    = (float*)p;                      p += npad * 32;
            unsigned* dstpart = (unsigned*)p;                   p += dstpart_sz;
            char* ov = p;
            unsigned*       outcnt   = (unsigned*)ov;
            unsigned*       outcnt_c = (unsigned*)(ov + npad * 4);
            unsigned short* srcpart  = (unsigned short*)(ov + npad * 4 + (size_t)CH_S * npad * 4);
            float*          accf_c   = (float*)ov;   // overlays A-view

            init_kernel<<<1, 256, 0, stream>>>(gcur, ovfc, nb, (int)cap);
            partition_kernel<<<NBLK1, 256, 0, stream>>>(src, dst, gcur, dstpart, srcpart,
                                                        ovfc, ovf_d, ovf_s, E, nb, (int)cap);
            srccount_kernel<<<nb * CH_S, 256, 0, stream>>>(gcur, srcpart, outcnt_c,
                                                           (int)cap, (int)npad, CH_S);
            red_outcnt_kernel<<<((int)npad + 255) / 256, 256, 0, stream>>>(outcnt_c, outcnt,
                                                                           (int)npad, CH_S);
            ovf_s_kernel<<<4, 256, 0, stream>>>(ovfc, ovf_s, outcnt);
            feat_kernel2<<<2048, 256, 0, stream>>>(h, W, outcnt, feat, n);
            if (cha >= 8) {
                // slab-sort accumulate: 1 LDS atomic/edge (needs cha==8 so
                // per-(node,chunk) load fits the 16-entry slab)
                accum3_kernel<<<nb * 8, 512, 0, stream>>>(gcur, dstpart, feat, accf_c,
                                                          ovfc, ovf_d, (int)cap, (int)npad, 8);
                ovf_d_kernel<<<4, 256, 0, stream>>>(ovfc, ovf_d, feat, accf_c);
                final2_kernel<<<(n + 255) / 256, 256, 0, stream>>>(accf_c, b, out, n,
                                                                   (int)npad, 8);
            } else {
                accum_kernel<<<nb * (int)cha, 512, 0, stream>>>(gcur, dstpart, feat, accf_c,
                                                                (int)cap, (int)npad, (int)cha);
                ovf_d_kernel<<<4, 256, 0, stream>>>(ovfc, ovf_d, feat, accf_c);
                final2_kernel<<<(n + 255) / 256, 256, 0, stream>>>(accf_c, b, out, n,
                                                                   (int)npad, (int)cha);
            }
            return;
        }
    }

    // ---------------- secondary: round-1 bucket path ----------------
    size_t fixed = (size_t)n * 4 * 2 + 64 + (size_t)n * 8 * 4 + (size_t)OVF_CAP * 8;
    int cap = 0;
    if (ws_size > fixed) cap = (int)((ws_size - fixed) / ((size_t)n * 4));
    if (cap > 96) cap = 96;

    if (cap >= 64) {
        unsigned* cursor = (unsigned*)d_ws;
        unsigned* outcnt = cursor + n;
        unsigned* ovfcnt = outcnt + n;
        float*    feat   = (float*)(ovfcnt + 16);
        unsigned* ovf    = (unsigned*)(feat + (size_t)n * 8);
        unsigned* bucket = ovf + (size_t)OVF_CAP * 2;

        hipMemsetAsync(d_ws, 0, (size_t)n * 8 + 64, stream);

        count_scatter_kernel<<<4096, 256, 0, stream>>>(src, dst, cursor, outcnt, bucket,
                                                       ovfcnt, ovf, E, cap);
        feat_kernel2<<<2048, 256, 0, stream>>>(h, W, outcnt, feat, n);
        gather_kernel<<<((size_t)n * 8 + 255) / 256, 256, 0, stream>>>(cursor, bucket, feat,
                                                                       b, out, n, cap);
        ovf_kernel<<<16, 256, 0, stream>>>(ovfcnt, ovf, feat, cursor, out);
        return;
    }

    // ---------------- tertiary: round-0 atomic path ----------------
    size_t need8 = (size_t)NXCD * n * 4 + (size_t)NXCD * n * FEAT_OUT * 4
                 + (size_t)n * 4 * 2 + (size_t)n * 8 * 4;
    int priv = (ws_size >= need8) ? 1 : 0;
    int NC = priv ? NXCD : 1;

    unsigned* deg_priv = (unsigned*)d_ws;
    float*    out_priv = (float*)(deg_priv + (size_t)NC * n);
    float*    norm_out = out_priv + (size_t)NC * n * FEAT_OUT;
    float*    norm_in  = norm_out + n;
    float*    feat     = norm_in + n;

    hipMemsetAsync(d_ws, 0, (size_t)NC * n * 4 * (1 + FEAT_OUT), stream);

    degree_kernel<<<4096, 256, 0, stream>>>(src, dst, deg_priv, E, n, priv);
    norm_kernel<<<(n + 255) / 256, 256, 0, stream>>>(deg_priv, norm_out, norm_in, n, NC);
    feat_kernel<<<2048, 256, 0, stream>>>(h, W, norm_out, feat, n);
    scatter_kernel<<<4096, 256, 0, stream>>>(src, dst, feat, out_priv, E, n, priv);
    final_kernel<<<(n + 255) / 256, 256, 0, stream>>>(out_priv, norm_in, b, out, n, NC);
}